// Round 2
// baseline (429.178 us; speedup 1.0000x reference)
//
#include <hip/hip_runtime.h>
#include <cstdint>

typedef float f32x4 __attribute__((ext_vector_type(4)));
typedef short s16x8 __attribute__((ext_vector_type(8)));

#define APAD 72   // padded LDS row (bf16 elems) for A/T tiles

__device__ __forceinline__ unsigned short f2bf(float f) {
  union { float f; uint32_t u; } v; v.f = f;
  uint32_t u = v.u;
  u += 0x7fffu + ((u >> 16) & 1u);
  return (unsigned short)(u >> 16);
}
__device__ __forceinline__ float bf2f(unsigned short h) {
  union { uint32_t u; float f; } v; v.u = ((uint32_t)h) << 16;
  return v.f;
}
__device__ __forceinline__ float sigmoidf_(float x) {
  return 1.0f / (1.0f + __expf(-x));
}
__device__ __forceinline__ f32x4 zero4() {
  f32x4 z = {0.f, 0.f, 0.f, 0.f};
  return z;
}
__device__ __forceinline__ void gl_lds16(const void* g, void* l) {
  __builtin_amdgcn_global_load_lds(
      (const __attribute__((address_space(1))) uint32_t*)g,
      (__attribute__((address_space(3))) uint32_t*)l, 16, 0, 0);
}

// ---------------------------------------------------------------------------
// prep: transpose 6 weight matrices [k][n] fp32 -> wt bf16 [m][n][64] (W^T packed)
// ---------------------------------------------------------------------------
__global__ __launch_bounds__(256) void k_prep(
    const float* __restrict__ Wlp, const float* __restrict__ Wrp,
    const float* __restrict__ Wlg, const float* __restrict__ Wrg,
    const float* __restrict__ Wog, const float* __restrict__ Wout,
    unsigned short* __restrict__ wt) {
  const float* srcs[6] = {Wlp, Wrp, Wlg, Wrg, Wog, Wout};
  const int m = blockIdx.x;
  const float* W = srcs[m];
  const int t = threadIdx.x;
  for (int e = t; e < 4096; e += 256) {
    const int n = e >> 6, k = e & 63;
    wt[m * 4096 + n * 64 + k] = f2bf(W[k * 64 + n]);
  }
}

// ---------------------------------------------------------------------------
// k1: x = LN(in); left=(x@Wlp+blp)*mask*sig(x@Wlg+blg); right analog.
//     writes leftT/rightT bf16 [B][C][L][L]. B-fragments read direct from L1.
// ---------------------------------------------------------------------------
__global__ __launch_bounds__(256, 4) void k1_proj(
    const float* __restrict__ xin, const float* __restrict__ mask,
    const float* __restrict__ lnw, const float* __restrict__ lnb,
    const float* __restrict__ blp, const float* __restrict__ brp,
    const float* __restrict__ blg, const float* __restrict__ brg,
    const unsigned short* __restrict__ wt,
    unsigned short* __restrict__ leftT, unsigned short* __restrict__ rightT) {
  __shared__ unsigned short A[64 * APAD];
  __shared__ unsigned short TL[64 * APAD];
  __shared__ unsigned short TR[64 * APAD];
  const int tid = threadIdx.x;
  const int bid = blockIdx.x;
  const int b = bid >> 12;
  const int i = (bid >> 3) & 511;
  const int k0 = (bid & 7) << 6;

  // load x rows + layernorm (4 threads per row, 16 ch each)
  const int p = tid >> 2, q = tid & 3;
  const float* xrow = xin + (((size_t)b * 512 + i) * 512 + k0 + p) * 64 + q * 16;
  f32x4 xv[4];
#pragma unroll
  for (int u = 0; u < 4; ++u) xv[u] = ((const f32x4*)xrow)[u];
  float s1 = 0.f, s2 = 0.f;
#pragma unroll
  for (int u = 0; u < 4; ++u)
#pragma unroll
    for (int e = 0; e < 4; ++e) { float t = xv[u][e]; s1 += t; s2 += t * t; }
  s1 += __shfl_xor(s1, 1); s2 += __shfl_xor(s2, 1);
  s1 += __shfl_xor(s1, 2); s2 += __shfl_xor(s2, 2);
  const float mu = s1 * 0.015625f;
  const float rs = rsqrtf(s2 * 0.015625f - mu * mu + 1e-5f);
  {
    uint32_t pk[8];
#pragma unroll
    for (int u = 0; u < 4; ++u) {
      f32x4 wv = ((const f32x4*)(lnw + q * 16))[u];
      f32x4 bv = ((const f32x4*)(lnb + q * 16))[u];
#pragma unroll
      for (int e2 = 0; e2 < 2; ++e2) {
        uint32_t lo = f2bf((xv[u][2 * e2] - mu) * rs * wv[2 * e2] + bv[2 * e2]);
        uint32_t hi = f2bf((xv[u][2 * e2 + 1] - mu) * rs * wv[2 * e2 + 1] + bv[2 * e2 + 1]);
        pk[u * 2 + e2] = lo | (hi << 16);
      }
    }
    uint32_t* a32 = (uint32_t*)&A[p * APAD + q * 16];
#pragma unroll
    for (int u = 0; u < 8; ++u) a32[u] = pk[u];
  }
  const float mval = mask[b * 512 + i];
  __syncthreads();

  // MFMA: A[64x64] @ W^T for 4 matrices, B-frags direct from global (L1)
  const int lane = tid & 63, w = tid >> 6;
  const int arow = (w * 16 + (lane & 15)) * APAD + ((lane >> 4) << 3);
  const s16x8 a0 = *(const s16x8*)&A[arow];
  const s16x8 a1 = *(const s16x8*)&A[arow + 32];
  const int bofs = ((lane & 15)) * 64 + ((lane >> 4) << 3);
  f32x4 acc[4][4];
#pragma unroll
  for (int m = 0; m < 4; ++m)
#pragma unroll
    for (int nf = 0; nf < 4; ++nf) acc[m][nf] = zero4();
#pragma unroll
  for (int m = 0; m < 4; ++m) {
#pragma unroll
    for (int nf = 0; nf < 4; ++nf) {
      const unsigned short* wb = wt + m * 4096 + nf * 1024 + bofs;
      const s16x8 b0 = *(const s16x8*)wb;
      const s16x8 b1 = *(const s16x8*)(wb + 32);
      acc[m][nf] = __builtin_amdgcn_mfma_f32_16x16x32_bf16(a0, b0, acc[m][nf], 0, 0, 0);
      acc[m][nf] = __builtin_amdgcn_mfma_f32_16x16x32_bf16(a1, b1, acc[m][nf], 0, 0, 0);
    }
  }

  const int fn = lane & 15;
  const int fr4 = (lane >> 4) << 2;
  const int prow = w * 16 + fr4;
  // combine + transpose into TL/TR (no intermediate sync)
#pragma unroll
  for (int nf = 0; nf < 4; ++nf) {
    const int n = nf * 16 + fn;
    {
      const float bl = blp[n], bg = blg[n];
      float v0 = (acc[0][nf][0] + bl) * mval * sigmoidf_(acc[2][nf][0] + bg);
      float v1 = (acc[0][nf][1] + bl) * mval * sigmoidf_(acc[2][nf][1] + bg);
      float v2 = (acc[0][nf][2] + bl) * mval * sigmoidf_(acc[2][nf][2] + bg);
      float v3 = (acc[0][nf][3] + bl) * mval * sigmoidf_(acc[2][nf][3] + bg);
      *(uint32_t*)&TL[n * APAD + prow] = (uint32_t)f2bf(v0) | ((uint32_t)f2bf(v1) << 16);
      *(uint32_t*)&TL[n * APAD + prow + 2] = (uint32_t)f2bf(v2) | ((uint32_t)f2bf(v3) << 16);
    }
    {
      const float bl = brp[n], bg = brg[n];
      float v0 = (acc[1][nf][0] + bl) * mval * sigmoidf_(acc[3][nf][0] + bg);
      float v1 = (acc[1][nf][1] + bl) * mval * sigmoidf_(acc[3][nf][1] + bg);
      float v2 = (acc[1][nf][2] + bl) * mval * sigmoidf_(acc[3][nf][2] + bg);
      float v3 = (acc[1][nf][3] + bl) * mval * sigmoidf_(acc[3][nf][3] + bg);
      *(uint32_t*)&TR[n * APAD + prow] = (uint32_t)f2bf(v0) | ((uint32_t)f2bf(v1) << 16);
      *(uint32_t*)&TR[n * APAD + prow + 2] = (uint32_t)f2bf(v2) | ((uint32_t)f2bf(v3) << 16);
    }
  }
  __syncthreads();
  {
    const int sn = tid >> 2, sq = tid & 3;
    const size_t gbase = (((size_t)b * 64 + sn) * 512 + i) * 512 + k0 + sq * 16;
    const uint32_t* sl = (const uint32_t*)&TL[sn * APAD + sq * 16];
    const uint32_t* sr = (const uint32_t*)&TR[sn * APAD + sq * 16];
    uint32_t* dl = (uint32_t*)(leftT + gbase);
    uint32_t* dr = (uint32_t*)(rightT + gbase);
#pragma unroll
    for (int u = 0; u < 8; ++u) dl[u] = sl[u];
#pragma unroll
    for (int u = 0; u < 8; ++u) dr[u] = sr[u];
  }
}

// ---------------------------------------------------------------------------
// k2: triT[b,c,i,j] = sum_k leftT[b,c,i,k] * rightT[b,c,j,k]
// ---------------------------------------------------------------------------
__global__ __launch_bounds__(256) void k2_gemm(
    const unsigned short* __restrict__ leftT,
    const unsigned short* __restrict__ rightT,
    unsigned short* __restrict__ triT) {
  __shared__ unsigned short Ab[2][128 * 64];
  __shared__ unsigned short Bb[2][128 * 64];
  const int tid = threadIdx.x, lane = tid & 63, w = tid >> 6;
  const int bid = blockIdx.x;
  const int sw = ((bid & 7) << 8) | (bid >> 3);
  const int plane = sw >> 4, tile = sw & 15;
  const size_t pb = (size_t)plane * 262144;
  const int i0 = (tile >> 2) << 7, j0 = (tile & 3) << 7;
  const int srow = lane >> 3;
  const int sk = (lane & 7) << 3;

  f32x4 acc[4][4];
#pragma unroll
  for (int mf = 0; mf < 4; ++mf)
#pragma unroll
    for (int nf = 0; nf < 4; ++nf) acc[mf][nf] = zero4();
  const int wr = (w >> 1) << 6, wc = (w & 1) << 6;

  auto stage = [&](int buf, int kt) {
    const int kk = kt << 6;
#pragma unroll
    for (int it = 0; it < 4; ++it) {
      const int ch = it * 4 + w;
      const int row = (ch << 3) + srow;
      gl_lds16(leftT + pb + (size_t)(i0 + row) * 512 + kk + sk,
               (char*)&Ab[buf][0] + ch * 1024 + lane * 16);
      gl_lds16(rightT + pb + (size_t)(j0 + row) * 512 + kk + sk,
               (char*)&Bb[buf][0] + ch * 1024 + lane * 16);
    }
  };

  stage(0, 0);
  for (int kt = 0; kt < 8; ++kt) {
    __syncthreads();
    if (kt < 7) stage((kt & 1) ^ 1, kt + 1);
    const unsigned short* Ac = &Ab[kt & 1][0];
    const unsigned short* Bc = &Bb[kt & 1][0];
#pragma unroll
    for (int ks = 0; ks < 2; ++ks) {
      const int ko = ((lane >> 4) << 3) + (ks << 5);
      s16x8 af[4], bfr[4];
#pragma unroll
      for (int mf = 0; mf < 4; ++mf)
        af[mf] = *(const s16x8*)&Ac[(wr + mf * 16 + (lane & 15)) * 64 + ko];
#pragma unroll
      for (int nf = 0; nf < 4; ++nf)
        bfr[nf] = *(const s16x8*)&Bc[(wc + nf * 16 + (lane & 15)) * 64 + ko];
#pragma unroll
      for (int mf = 0; mf < 4; ++mf)
#pragma unroll
        for (int nf = 0; nf < 4; ++nf)
          acc[mf][nf] = __builtin_amdgcn_mfma_f32_16x16x32_bf16(af[mf], bfr[nf], acc[mf][nf], 0, 0, 0);
    }
  }
  __syncthreads();
  unsigned short* Tt = &Ab[0][0];
#pragma unroll
  for (int mf = 0; mf < 4; ++mf)
#pragma unroll
    for (int nf = 0; nf < 4; ++nf) {
      const int col = wc + nf * 16 + (lane & 15);
#pragma unroll
      for (int r = 0; r < 4; ++r) {
        const int row = wr + mf * 16 + ((lane >> 4) << 2) + r;
        Tt[row * 128 + col] = f2bf(acc[mf][nf][r]);
      }
    }
  __syncthreads();
  {
    const int row = tid >> 1, half = (tid & 1) << 6;
    const uint32_t* src = (const uint32_t*)&Tt[row * 128 + half];
    uint32_t* dst = (uint32_t*)(triT + pb + (size_t)(i0 + row) * 512 + j0 + half);
#pragma unroll
    for (int u = 0; u < 32; ++u) dst[u] = src[u];
  }
}

// ---------------------------------------------------------------------------
// k3: y = LN_out(tri) * sigmoid(LN_in(resid)@Wog+bog); out = y@Wout+bout+resid
// ---------------------------------------------------------------------------
#define OPAD 68   // padded f32 out-tile row
__global__ __launch_bounds__(256, 4) void k3_out(
    const unsigned short* __restrict__ triT,
    const float* __restrict__ resid,
    const float* __restrict__ lnw1, const float* __restrict__ lnb1,
    const float* __restrict__ bog,
    const float* __restrict__ lnw2, const float* __restrict__ lnb2,
    const float* __restrict__ bout,
    const unsigned short* __restrict__ wt,
    float* __restrict__ outp) {
  __shared__ __align__(16) unsigned char smem[27648];
  unsigned short* Y  = (unsigned short*)smem;             // [64][APAD] bf16
  unsigned short* X  = (unsigned short*)(smem + 9216);    // [64][APAD] bf16
  unsigned short* OG = (unsigned short*)(smem + 18432);   // [64][APAD] bf16
  float* OUT32 = (float*)(smem + 9216);                   // [64][OPAD] f32 (aliases X,OG)
  const int tid = threadIdx.x, lane = tid & 63, w = tid >> 6;
  const int bid = blockIdx.x;
  const int b = bid >> 12;
  const int i = (bid >> 3) & 511;
  const int j0 = (bid & 7) << 6;

  const int j = tid >> 2, q = tid & 3;
  // phase 1: tri tile -> transposed Y[j][c]; resid LN -> X
  {
    const int c = tid >> 2;
    const size_t srow = ((size_t)(b * 64 + c) * 512 + i) * 512 + j0 + q * 16;
    union { uint32_t u32[8]; unsigned short s[16]; } uu;
    const uint32_t* s32 = (const uint32_t*)(triT + srow);
#pragma unroll
    for (int u = 0; u < 8; ++u) uu.u32[u] = s32[u];
#pragma unroll
    for (int s = 0; s < 16; ++s) Y[(q * 16 + s) * APAD + c] = uu.s[s];
  }
  {
    const float* rrow = resid + (((size_t)b * 512 + i) * 512 + j0 + j) * 64 + q * 16;
    f32x4 rv[4];
#pragma unroll
    for (int u = 0; u < 4; ++u) rv[u] = ((const f32x4*)rrow)[u];
    float s1 = 0.f, s2 = 0.f;
#pragma unroll
    for (int u = 0; u < 4; ++u)
#pragma unroll
      for (int e = 0; e < 4; ++e) { float t = rv[u][e]; s1 += t; s2 += t * t; }
    s1 += __shfl_xor(s1, 1); s2 += __shfl_xor(s2, 1);
    s1 += __shfl_xor(s1, 2); s2 += __shfl_xor(s2, 2);
    const float mu = s1 * 0.015625f;
    const float rs = rsqrtf(s2 * 0.015625f - mu * mu + 1e-5f);
    uint32_t pk[8];
#pragma unroll
    for (int u = 0; u < 4; ++u) {
      f32x4 wv = ((const f32x4*)(lnw1 + q * 16))[u];
      f32x4 bv = ((const f32x4*)(lnb1 + q * 16))[u];
#pragma unroll
      for (int e2 = 0; e2 < 2; ++e2) {
        uint32_t lo = f2bf((rv[u][2 * e2] - mu) * rs * wv[2 * e2] + bv[2 * e2]);
        uint32_t hi = f2bf((rv[u][2 * e2 + 1] - mu) * rs * wv[2 * e2 + 1] + bv[2 * e2 + 1]);
        pk[u * 2 + e2] = lo | (hi << 16);
      }
    }
    uint32_t* x32 = (uint32_t*)&X[j * APAD + q * 16];
#pragma unroll
    for (int u = 0; u < 8; ++u) x32[u] = pk[u];
  }
  __syncthreads();

  // phase 2: tri LN stats (regs) + og MFMA
  float yv[16];
  {
    union { uint32_t u32[8]; unsigned short s[16]; } uy;
    const uint32_t* y32 = (const uint32_t*)&Y[j * APAD + q * 16];
#pragma unroll
    for (int u = 0; u < 8; ++u) uy.u32[u] = y32[u];
#pragma unroll
    for (int s = 0; s < 16; ++s) yv[s] = bf2f(uy.s[s]);
  }
  float t1 = 0.f, t2 = 0.f;
#pragma unroll
  for (int s = 0; s < 16; ++s) { t1 += yv[s]; t2 += yv[s] * yv[s]; }
  t1 += __shfl_xor(t1, 1); t2 += __shfl_xor(t2, 1);
  t1 += __shfl_xor(t1, 2); t2 += __shfl_xor(t2, 2);
  const float mu2 = t1 * 0.015625f;
  const float rs2 = rsqrtf(t2 * 0.015625f - mu2 * mu2 + 1e-5f);

  const int arow = (w * 16 + (lane & 15)) * APAD + ((lane >> 4) << 3);
  const int bofs = (lane & 15) * 64 + ((lane >> 4) << 3);
  {
    const s16x8 a0 = *(const s16x8*)&X[arow];
    const s16x8 a1 = *(const s16x8*)&X[arow + 32];
    f32x4 aog[4];
#pragma unroll
    for (int nf = 0; nf < 4; ++nf) aog[nf] = zero4();
#pragma unroll
    for (int nf = 0; nf < 4; ++nf) {
      const unsigned short* wb = wt + 4 * 4096 + nf * 1024 + bofs;
      const s16x8 b0 = *(const s16x8*)wb;
      const s16x8 b1 = *(const s16x8*)(wb + 32);
      aog[nf] = __builtin_amdgcn_mfma_f32_16x16x32_bf16(a0, b0, aog[nf], 0, 0, 0);
      aog[nf] = __builtin_amdgcn_mfma_f32_16x16x32_bf16(a1, b1, aog[nf], 0, 0, 0);
    }
#pragma unroll
    for (int nf = 0; nf < 4; ++nf) {
      const int n = nf * 16 + (lane & 15);
      const float bb = bog[n];
#pragma unroll
      for (int r = 0; r < 4; ++r) {
        const int prow = w * 16 + ((lane >> 4) << 2) + r;
        OG[prow * APAD + n] = f2bf(sigmoidf_(aog[nf][r] + bb));
      }
    }
  }
  __syncthreads();

  // phase 3: y = LN_out(tri) * og -> Y bf16
  {
    union { uint32_t u32[8]; unsigned short s[16]; } og_;
    const uint32_t* o32 = (const uint32_t*)&OG[j * APAD + q * 16];
#pragma unroll
    for (int u = 0; u < 8; ++u) og_.u32[u] = o32[u];
    uint32_t pk[8];
#pragma unroll
    for (int u = 0; u < 4; ++u) {
      f32x4 wv = ((const f32x4*)(lnw2 + q * 16))[u];
      f32x4 bv = ((const f32x4*)(lnb2 + q * 16))[u];
#pragma unroll
      for (int e2 = 0; e2 < 2; ++e2) {
        const int s0 = u * 4 + 2 * e2;
        float y0 = ((yv[s0] - mu2) * rs2 * wv[2 * e2] + bv[2 * e2]) * bf2f(og_.s[s0]);
        float y1 = ((yv[s0 + 1] - mu2) * rs2 * wv[2 * e2 + 1] + bv[2 * e2 + 1]) * bf2f(og_.s[s0 + 1]);
        pk[u * 2 + e2] = (uint32_t)f2bf(y0) | ((uint32_t)f2bf(y1) << 16);
      }
    }
    uint32_t* y32 = (uint32_t*)&Y[j * APAD + q * 16];
#pragma unroll
    for (int u = 0; u < 8; ++u) y32[u] = pk[u];
  }
  __syncthreads();

  // phase 4: out = Y @ Wout + bout -> OUT32 (LDS, padded)
  {
    const s16x8 a0 = *(const s16x8*)&Y[arow];
    const s16x8 a1 = *(const s16x8*)&Y[arow + 32];
    f32x4 ao[4];
#pragma unroll
    for (int nf = 0; nf < 4; ++nf) ao[nf] = zero4();
#pragma unroll
    for (int nf = 0; nf < 4; ++nf) {
      const unsigned short* wb = wt + 5 * 4096 + nf * 1024 + bofs;
      const s16x8 b0 = *(const s16x8*)wb;
      const s16x8 b1 = *(const s16x8*)(wb + 32);
      ao[nf] = __builtin_amdgcn_mfma_f32_16x16x32_bf16(a0, b0, ao[nf], 0, 0, 0);
      ao[nf] = __builtin_amdgcn_mfma_f32_16x16x32_bf16(a1, b1, ao[nf], 0, 0, 0);
    }
#pragma unroll
    for (int nf = 0; nf < 4; ++nf) {
      const int n = nf * 16 + (lane & 15);
      const float bo = bout[n];
#pragma unroll
      for (int r = 0; r < 4; ++r) {
        const int prow = w * 16 + ((lane >> 4) << 2) + r;
        OUT32[prow * OPAD + n] = ao[nf][r] + bo;
      }
    }
  }
  __syncthreads();

  // phase 5: coalesced residual add + store
  {
    const int r = tid >> 2, rq = tid & 3;
    const size_t gb = (((size_t)b * 512 + i) * 512 + j0 + r) * 64 + rq * 16;
    const float* rr = resid + gb;
    float* op = outp + gb;
#pragma unroll
    for (int u = 0; u < 4; ++u) {
      f32x4 ov = ((const f32x4*)&OUT32[r * OPAD + rq * 16])[u];
      f32x4 rv = ((const f32x4*)rr)[u];
      ((f32x4*)op)[u] = ov + rv;
    }
  }
}

// ---------------------------------------------------------------------------
extern "C" void kernel_launch(void* const* d_in, const int* in_sizes, int n_in,
                              void* d_out, int out_size, void* d_ws, size_t ws_size,
                              hipStream_t stream) {
  const float* x     = (const float*)d_in[0];
  const float* mask  = (const float*)d_in[1];
  const float* lnw1  = (const float*)d_in[2];
  const float* lnb1  = (const float*)d_in[3];
  const float* Wlp   = (const float*)d_in[4];
  const float* blp   = (const float*)d_in[5];
  const float* Wrp   = (const float*)d_in[6];
  const float* brp   = (const float*)d_in[7];
  const float* Wlg   = (const float*)d_in[8];
  const float* blg   = (const float*)d_in[9];
  const float* Wrg   = (const float*)d_in[10];
  const float* brg   = (const float*)d_in[11];
  const float* Wog   = (const float*)d_in[12];
  const float* bog   = (const float*)d_in[13];
  const float* lnw2  = (const float*)d_in[14];
  const float* lnb2  = (const float*)d_in[15];
  const float* Wout  = (const float*)d_in[16];
  const float* bout  = (const float*)d_in[17];

  unsigned short* leftT  = (unsigned short*)d_ws;
  unsigned short* rightT = leftT + (size_t)33554432;
  unsigned short* triT   = rightT + (size_t)33554432;
  unsigned short* wt     = triT + (size_t)33554432;   // 6*64*64 bf16 packed

  k_prep<<<6, 256, 0, stream>>>(Wlp, Wrp, Wlg, Wrg, Wog, Wout, wt);
  k1_proj<<<8192, 256, 0, stream>>>(x, mask, lnw1, lnb1, blp, brp, blg, brg,
                                    wt, leftT, rightT);
  k2_gemm<<<2048, 256, 0, stream>>>(leftT, rightT, triT);
  k3_out<<<8192, 256, 0, stream>>>(triT, x, lnw1, lnb1, bog, lnw2, lnb2, bout,
                                   wt, (float*)d_out);
}

// Round 3
// 306.503 us; speedup vs baseline: 1.4002x; 1.4002x over previous
//
#include <hip/hip_runtime.h>
#include <cstdint>

typedef float f32x4 __attribute__((ext_vector_type(4)));
typedef short s16x8 __attribute__((ext_vector_type(8)));

#define APAD 72   // padded row (bf16 elems): 144 B rows, 2-way-conflict floor

__device__ __forceinline__ unsigned short f2bf(float f) {
  union { float f; uint32_t u; } v; v.f = f;
  uint32_t u = v.u;
  u += 0x7fffu + ((u >> 16) & 1u);
  return (unsigned short)(u >> 16);
}
__device__ __forceinline__ float bf2f(unsigned short h) {
  union { uint32_t u; float f; } v; v.u = ((uint32_t)h) << 16;
  return v.f;
}
__device__ __forceinline__ float sigmoidf_(float x) {
  return 1.0f / (1.0f + __expf(-x));
}
__device__ __forceinline__ f32x4 zero4() {
  f32x4 z = {0.f, 0.f, 0.f, 0.f};
  return z;
}
__device__ __forceinline__ void gl_lds16(const void* g, void* l) {
  __builtin_amdgcn_global_load_lds(
      (const __attribute__((address_space(1))) uint32_t*)g,
      (__attribute__((address_space(3))) uint32_t*)l, 16, 0, 0);
}

// ---------------------------------------------------------------------------
// prep: transpose 6 weight matrices [k][n] fp32 -> wt bf16 [m][n][APAD] (W^T,
// zero-padded rows so k3 can blit linearly with global_load_lds)
// ---------------------------------------------------------------------------
__global__ __launch_bounds__(256) void k_prep(
    const float* __restrict__ Wlp, const float* __restrict__ Wrp,
    const float* __restrict__ Wlg, const float* __restrict__ Wrg,
    const float* __restrict__ Wog, const float* __restrict__ Wout,
    unsigned short* __restrict__ wt) {
  const float* srcs[6] = {Wlp, Wrp, Wlg, Wrg, Wog, Wout};
  const int m = blockIdx.x;
  const float* W = srcs[m];
  const int t = threadIdx.x;
  for (int e = t; e < 64 * APAD; e += 256) {
    const int n = e / APAD, k = e - n * APAD;
    wt[m * (64 * APAD) + e] = (k < 64) ? f2bf(W[k * 64 + n]) : (unsigned short)0;
  }
}

// ---------------------------------------------------------------------------
// k1: x = LN(in); left=(x@Wlp+blp)*mask*sig(x@Wlg+blg); right analog.
// Wave w = (pair = w>>1 selects left/right, ch = w&1 selects col half).
// Each wave: all 64 rows x 32 cols for product+gate, weights held in VGPRs.
// ---------------------------------------------------------------------------
__global__ __launch_bounds__(256, 4) void k1_proj(
    const float* __restrict__ xin, const float* __restrict__ mask,
    const float* __restrict__ lnw, const float* __restrict__ lnb,
    const float* __restrict__ blp, const float* __restrict__ brp,
    const float* __restrict__ blg, const float* __restrict__ brg,
    const unsigned short* __restrict__ wt,
    unsigned short* __restrict__ leftT, unsigned short* __restrict__ rightT) {
  __shared__ unsigned short A[64 * APAD];
  __shared__ unsigned short TL[64 * APAD];
  __shared__ unsigned short TR[64 * APAD];
  const int tid = threadIdx.x, lane = tid & 63, w = tid >> 6;
  const int bid = blockIdx.x;
  const int b = bid >> 12;
  const int i = (bid >> 3) & 511;
  const int k0 = (bid & 7) << 6;

  // ---- per-wave weight fragments -> VGPRs (hoisted; hidden under LN) ----
  const int pair = w >> 1, ch = w & 1;
  const int kh8 = (lane >> 4) << 3;
  s16x8 wp[2][2], wg[2][2];       // [nf2][k-half]
  float bPv[2], bGv[2];
  {
    const unsigned short* wtP = wt + (size_t)pair * (64 * APAD);        // lp / rp
    const unsigned short* wtG = wt + (size_t)(2 + pair) * (64 * APAD);  // lg / rg
    const float* bP = pair ? brp : blp;
    const float* bG = pair ? brg : blg;
#pragma unroll
    for (int nf2 = 0; nf2 < 2; ++nf2) {
      const int n = ch * 32 + nf2 * 16 + (lane & 15);
      const unsigned short* pp = wtP + n * APAD + kh8;
      const unsigned short* pg = wtG + n * APAD + kh8;
      wp[nf2][0] = *(const s16x8*)pp;  wp[nf2][1] = *(const s16x8*)(pp + 32);
      wg[nf2][0] = *(const s16x8*)pg;  wg[nf2][1] = *(const s16x8*)(pg + 32);
      bPv[nf2] = bP[n];  bGv[nf2] = bG[n];
    }
  }

  // ---- load x rows + layernorm (4 threads per row, 16 ch each) ----
  const int p = tid >> 2, q = tid & 3;
  const float* xrow = xin + (((size_t)b * 512 + i) * 512 + k0 + p) * 64 + q * 16;
  f32x4 xv[4];
#pragma unroll
  for (int u = 0; u < 4; ++u) xv[u] = ((const f32x4*)xrow)[u];
  float s1 = 0.f, s2 = 0.f;
#pragma unroll
  for (int u = 0; u < 4; ++u)
#pragma unroll
    for (int e = 0; e < 4; ++e) { float t = xv[u][e]; s1 += t; s2 += t * t; }
  s1 += __shfl_xor(s1, 1); s2 += __shfl_xor(s2, 1);
  s1 += __shfl_xor(s1, 2); s2 += __shfl_xor(s2, 2);
  const float mu = s1 * 0.015625f;
  const float rs = rsqrtf(s2 * 0.015625f - mu * mu + 1e-5f);
  {
    uint32_t pk[8];
#pragma unroll
    for (int u = 0; u < 4; ++u) {
      f32x4 wv = ((const f32x4*)(lnw + q * 16))[u];
      f32x4 bv = ((const f32x4*)(lnb + q * 16))[u];
#pragma unroll
      for (int e2 = 0; e2 < 2; ++e2) {
        uint32_t lo = f2bf((xv[u][2 * e2] - mu) * rs * wv[2 * e2] + bv[2 * e2]);
        uint32_t hi = f2bf((xv[u][2 * e2 + 1] - mu) * rs * wv[2 * e2 + 1] + bv[2 * e2 + 1]);
        pk[u * 2 + e2] = lo | (hi << 16);
      }
    }
    uint32_t* a32 = (uint32_t*)&A[p * APAD + q * 16];
#pragma unroll
    for (int u = 0; u < 8; ++u) a32[u] = pk[u];
  }
  const float mval = mask[b * 512 + i];
  __syncthreads();

  // ---- MFMA + wave-local combine + transpose ----
  const int fr4 = (lane >> 4) << 2;
  unsigned short* T = pair ? TR : TL;
#pragma unroll
  for (int mf = 0; mf < 4; ++mf) {
    const int ar = (mf * 16 + (lane & 15)) * APAD + kh8;
    const s16x8 a0 = *(const s16x8*)&A[ar];
    const s16x8 a1 = *(const s16x8*)&A[ar + 32];
    f32x4 accP[2], accG[2];
#pragma unroll
    for (int nf2 = 0; nf2 < 2; ++nf2) {
      accP[nf2] = zero4(); accG[nf2] = zero4();
      accP[nf2] = __builtin_amdgcn_mfma_f32_16x16x32_bf16(a0, wp[nf2][0], accP[nf2], 0, 0, 0);
      accP[nf2] = __builtin_amdgcn_mfma_f32_16x16x32_bf16(a1, wp[nf2][1], accP[nf2], 0, 0, 0);
      accG[nf2] = __builtin_amdgcn_mfma_f32_16x16x32_bf16(a0, wg[nf2][0], accG[nf2], 0, 0, 0);
      accG[nf2] = __builtin_amdgcn_mfma_f32_16x16x32_bf16(a1, wg[nf2][1], accG[nf2], 0, 0, 0);
    }
    const int prow = mf * 16 + fr4;
#pragma unroll
    for (int nf2 = 0; nf2 < 2; ++nf2) {
      const int n = ch * 32 + nf2 * 16 + (lane & 15);
      const float bl = bPv[nf2], bg = bGv[nf2];
      float v0 = (accP[nf2][0] + bl) * mval * sigmoidf_(accG[nf2][0] + bg);
      float v1 = (accP[nf2][1] + bl) * mval * sigmoidf_(accG[nf2][1] + bg);
      float v2 = (accP[nf2][2] + bl) * mval * sigmoidf_(accG[nf2][2] + bg);
      float v3 = (accP[nf2][3] + bl) * mval * sigmoidf_(accG[nf2][3] + bg);
      *(uint32_t*)&T[n * APAD + prow] = (uint32_t)f2bf(v0) | ((uint32_t)f2bf(v1) << 16);
      *(uint32_t*)&T[n * APAD + prow + 2] = (uint32_t)f2bf(v2) | ((uint32_t)f2bf(v3) << 16);
    }
  }
  __syncthreads();

  // ---- coalesced stores of both transposed tiles ----
  {
    const int sn = tid >> 2, sq = tid & 3;
    const size_t gbase = (((size_t)b * 64 + sn) * 512 + i) * 512 + k0 + sq * 16;
    const uint32_t* sl = (const uint32_t*)&TL[sn * APAD + sq * 16];
    const uint32_t* sr = (const uint32_t*)&TR[sn * APAD + sq * 16];
    uint32_t* dl = (uint32_t*)(leftT + gbase);
    uint32_t* dr = (uint32_t*)(rightT + gbase);
#pragma unroll
    for (int u = 0; u < 8; ++u) dl[u] = sl[u];
#pragma unroll
    for (int u = 0; u < 8; ++u) dr[u] = sr[u];
  }
}

// ---------------------------------------------------------------------------
// k2: triT[b,c,i,j] = sum_k leftT[b,c,i,k] * rightT[b,c,j,k]
// ---------------------------------------------------------------------------
__global__ __launch_bounds__(256) void k2_gemm(
    const unsigned short* __restrict__ leftT,
    const unsigned short* __restrict__ rightT,
    unsigned short* __restrict__ triT) {
  __shared__ unsigned short Ab[2][128 * 64];
  __shared__ unsigned short Bb[2][128 * 64];
  const int tid = threadIdx.x, lane = tid & 63, w = tid >> 6;
  const int bid = blockIdx.x;
  const int sw = ((bid & 7) << 8) | (bid >> 3);
  const int plane = sw >> 4, tile = sw & 15;
  const size_t pb = (size_t)plane * 262144;
  const int i0 = (tile >> 2) << 7, j0 = (tile & 3) << 7;
  const int srow = lane >> 3;
  const int sk = (lane & 7) << 3;

  f32x4 acc[4][4];
#pragma unroll
  for (int mf = 0; mf < 4; ++mf)
#pragma unroll
    for (int nf = 0; nf < 4; ++nf) acc[mf][nf] = zero4();
  const int wr = (w >> 1) << 6, wc = (w & 1) << 6;

  auto stage = [&](int buf, int kt) {
    const int kk = kt << 6;
#pragma unroll
    for (int it = 0; it < 4; ++it) {
      const int ch = it * 4 + w;
      const int row = (ch << 3) + srow;
      gl_lds16(leftT + pb + (size_t)(i0 + row) * 512 + kk + sk,
               (char*)&Ab[buf][0] + ch * 1024 + lane * 16);
      gl_lds16(rightT + pb + (size_t)(j0 + row) * 512 + kk + sk,
               (char*)&Bb[buf][0] + ch * 1024 + lane * 16);
    }
  };

  stage(0, 0);
  for (int kt = 0; kt < 8; ++kt) {
    __syncthreads();
    if (kt < 7) stage((kt & 1) ^ 1, kt + 1);
    const unsigned short* Ac = &Ab[kt & 1][0];
    const unsigned short* Bc = &Bb[kt & 1][0];
#pragma unroll
    for (int ks = 0; ks < 2; ++ks) {
      const int ko = ((lane >> 4) << 3) + (ks << 5);
      s16x8 af[4], bfr[4];
#pragma unroll
      for (int mf = 0; mf < 4; ++mf)
        af[mf] = *(const s16x8*)&Ac[(wr + mf * 16 + (lane & 15)) * 64 + ko];
#pragma unroll
      for (int nf = 0; nf < 4; ++nf)
        bfr[nf] = *(const s16x8*)&Bc[(wc + nf * 16 + (lane & 15)) * 64 + ko];
#pragma unroll
      for (int mf = 0; mf < 4; ++mf)
#pragma unroll
        for (int nf = 0; nf < 4; ++nf)
          acc[mf][nf] = __builtin_amdgcn_mfma_f32_16x16x32_bf16(af[mf], bfr[nf], acc[mf][nf], 0, 0, 0);
    }
  }
  __syncthreads();
  unsigned short* Tt = &Ab[0][0];
#pragma unroll
  for (int mf = 0; mf < 4; ++mf)
#pragma unroll
    for (int nf = 0; nf < 4; ++nf) {
      const int col = wc + nf * 16 + (lane & 15);
#pragma unroll
      for (int r = 0; r < 4; ++r) {
        const int row = wr + mf * 16 + ((lane >> 4) << 2) + r;
        Tt[row * 128 + col] = f2bf(acc[mf][nf][r]);
      }
    }
  __syncthreads();
  {
    const int row = tid >> 1, half = (tid & 1) << 6;
    const uint32_t* src = (const uint32_t*)&Tt[row * 128 + half];
    uint32_t* dst = (uint32_t*)(triT + pb + (size_t)(i0 + row) * 512 + j0 + half);
#pragma unroll
    for (int u = 0; u < 32; ++u) dst[u] = src[u];
  }
}

// ---------------------------------------------------------------------------
// k3: y = LN_out(tri) * sigmoid(LN_in(resid)@Wog+bog); out = y@Wout+bout+resid
// Weights async-staged to LDS at entry; drained by the phase-1 sync.
// ---------------------------------------------------------------------------
#define OPAD 68   // padded f32 out-tile row
__global__ __launch_bounds__(256, 3) void k3_out(
    const unsigned short* __restrict__ triT,
    const float* __restrict__ resid,
    const float* __restrict__ lnw1, const float* __restrict__ lnb1,
    const float* __restrict__ bog,
    const float* __restrict__ lnw2, const float* __restrict__ lnb2,
    const float* __restrict__ bout,
    const unsigned short* __restrict__ wt,
    float* __restrict__ outp) {
  __shared__ __align__(16) unsigned char smem[18432 + 27648];
  unsigned short* WT = (unsigned short*)smem;                     // [2][64][APAD]
  unsigned short* Y  = (unsigned short*)(smem + 18432);           // [64][APAD]
  unsigned short* X  = (unsigned short*)(smem + 18432 + 9216);    // [64][APAD]
  unsigned short* OG = (unsigned short*)(smem + 18432 + 18432);   // [64][APAD]
  float* OUT32 = (float*)(smem + 18432 + 9216);                   // aliases X,OG
  const int tid = threadIdx.x, lane = tid & 63, w = tid >> 6;
  const int bid = blockIdx.x;
  const int b = bid >> 12;
  const int i = (bid >> 3) & 511;
  const int j0 = (bid & 7) << 6;

  // async-stage og^T and out^T (18432 B), overlapped with phase 1
  const char* wsrc = (const char*)(wt + (size_t)4 * (64 * APAD));
#pragma unroll
  for (int it = 0; it < 5; ++it) {
    const int off = (it * 256 + tid) * 16;
    if (off < 18432) gl_lds16(wsrc + off, (char*)WT + off);
  }

  const int j = tid >> 2, q = tid & 3;
  // phase 1: tri tile -> transposed Y[j][c]; resid LN -> X
  {
    const int c = tid >> 2;
    const size_t srow = ((size_t)(b * 64 + c) * 512 + i) * 512 + j0 + q * 16;
    union { uint32_t u32[8]; unsigned short s[16]; } uu;
    const uint32_t* s32 = (const uint32_t*)(triT + srow);
#pragma unroll
    for (int u = 0; u < 8; ++u) uu.u32[u] = s32[u];
#pragma unroll
    for (int s = 0; s < 16; ++s) Y[(q * 16 + s) * APAD + c] = uu.s[s];
  }
  {
    const float* rrow = resid + (((size_t)b * 512 + i) * 512 + j0 + j) * 64 + q * 16;
    f32x4 rv[4];
#pragma unroll
    for (int u = 0; u < 4; ++u) rv[u] = ((const f32x4*)rrow)[u];
    float s1 = 0.f, s2 = 0.f;
#pragma unroll
    for (int u = 0; u < 4; ++u)
#pragma unroll
      for (int e = 0; e < 4; ++e) { float t = rv[u][e]; s1 += t; s2 += t * t; }
    s1 += __shfl_xor(s1, 1); s2 += __shfl_xor(s2, 1);
    s1 += __shfl_xor(s1, 2); s2 += __shfl_xor(s2, 2);
    const float mu = s1 * 0.015625f;
    const float rs = rsqrtf(s2 * 0.015625f - mu * mu + 1e-5f);
    uint32_t pk[8];
#pragma unroll
    for (int u = 0; u < 4; ++u) {
      f32x4 wv = ((const f32x4*)(lnw1 + q * 16))[u];
      f32x4 bv = ((const f32x4*)(lnb1 + q * 16))[u];
#pragma unroll
      for (int e2 = 0; e2 < 2; ++e2) {
        uint32_t lo = f2bf((rv[u][2 * e2] - mu) * rs * wv[2 * e2] + bv[2 * e2]);
        uint32_t hi = f2bf((rv[u][2 * e2 + 1] - mu) * rs * wv[2 * e2 + 1] + bv[2 * e2 + 1]);
        pk[u * 2 + e2] = lo | (hi << 16);
      }
    }
    uint32_t* x32 = (uint32_t*)&X[j * APAD + q * 16];
#pragma unroll
    for (int u = 0; u < 8; ++u) x32[u] = pk[u];
  }
  __syncthreads();

  // phase 2: tri LN stats (regs) + og MFMA
  float yv[16];
  {
    union { uint32_t u32[8]; unsigned short s[16]; } uy;
    const uint32_t* y32 = (const uint32_t*)&Y[j * APAD + q * 16];
#pragma unroll
    for (int u = 0; u < 8; ++u) uy.u32[u] = y32[u];
#pragma unroll
    for (int s = 0; s < 16; ++s) yv[s] = bf2f(uy.s[s]);
  }
  float t1 = 0.f, t2 = 0.f;
#pragma unroll
  for (int s = 0; s < 16; ++s) { t1 += yv[s]; t2 += yv[s] * yv[s]; }
  t1 += __shfl_xor(t1, 1); t2 += __shfl_xor(t2, 1);
  t1 += __shfl_xor(t1, 2); t2 += __shfl_xor(t2, 2);
  const float mu2 = t1 * 0.015625f;
  const float rs2 = rsqrtf(t2 * 0.015625f - mu2 * mu2 + 1e-5f);

  const int arow = (w * 16 + (lane & 15)) * APAD + ((lane >> 4) << 3);
  {
    const s16x8 a0 = *(const s16x8*)&X[arow];
    const s16x8 a1 = *(const s16x8*)&X[arow + 32];
    f32x4 aog[4];
#pragma unroll
    for (int nf = 0; nf < 4; ++nf) aog[nf] = zero4();
#pragma unroll
    for (int nf = 0; nf < 4; ++nf) {
      const int brow = (nf * 16 + (lane & 15)) * APAD + ((lane >> 4) << 3);
      const s16x8 b0 = *(const s16x8*)&WT[brow];
      const s16x8 b1 = *(const s16x8*)&WT[brow + 32];
      aog[nf] = __builtin_amdgcn_mfma_f32_16x16x32_bf16(a0, b0, aog[nf], 0, 0, 0);
      aog[nf] = __builtin_amdgcn_mfma_f32_16x16x32_bf16(a1, b1, aog[nf], 0, 0, 0);
    }
#pragma unroll
    for (int nf = 0; nf < 4; ++nf) {
      const int n = nf * 16 + (lane & 15);
      const float bb = bog[n];
#pragma unroll
      for (int r = 0; r < 4; ++r) {
        const int prow = w * 16 + ((lane >> 4) << 2) + r;
        OG[prow * APAD + n] = f2bf(sigmoidf_(aog[nf][r] + bb));
      }
    }
  }
  __syncthreads();

  // phase 3: y = LN_out(tri) * og -> Y bf16
  {
    union { uint32_t u32[8]; unsigned short s[16]; } og_;
    const uint32_t* o32 = (const uint32_t*)&OG[j * APAD + q * 16];
#pragma unroll
    for (int u = 0; u < 8; ++u) og_.u32[u] = o32[u];
    uint32_t pk[8];
#pragma unroll
    for (int u = 0; u < 4; ++u) {
      f32x4 wv = ((const f32x4*)(lnw2 + q * 16))[u];
      f32x4 bv = ((const f32x4*)(lnb2 + q * 16))[u];
#pragma unroll
      for (int e2 = 0; e2 < 2; ++e2) {
        const int s0 = u * 4 + 2 * e2;
        float y0 = ((yv[s0] - mu2) * rs2 * wv[2 * e2] + bv[2 * e2]) * bf2f(og_.s[s0]);
        float y1 = ((yv[s0 + 1] - mu2) * rs2 * wv[2 * e2 + 1] + bv[2 * e2 + 1]) * bf2f(og_.s[s0 + 1]);
        pk[u * 2 + e2] = (uint32_t)f2bf(y0) | ((uint32_t)f2bf(y1) << 16);
      }
    }
    uint32_t* y32 = (uint32_t*)&Y[j * APAD + q * 16];
#pragma unroll
    for (int u = 0; u < 8; ++u) y32[u] = pk[u];
  }
  __syncthreads();

  // phase 4: out = Y @ Wout + bout -> OUT32 (LDS, padded)
  {
    const s16x8 a0 = *(const s16x8*)&Y[arow];
    const s16x8 a1 = *(const s16x8*)&Y[arow + 32];
    f32x4 ao[4];
#pragma unroll
    for (int nf = 0; nf < 4; ++nf) ao[nf] = zero4();
#pragma unroll
    for (int nf = 0; nf < 4; ++nf) {
      const int brow = 64 * APAD + (nf * 16 + (lane & 15)) * APAD + ((lane >> 4) << 3);
      const s16x8 b0 = *(const s16x8*)&WT[brow];
      const s16x8 b1 = *(const s16x8*)&WT[brow + 32];
      ao[nf] = __builtin_amdgcn_mfma_f32_16x16x32_bf16(a0, b0, ao[nf], 0, 0, 0);
      ao[nf] = __builtin_amdgcn_mfma_f32_16x16x32_bf16(a1, b1, ao[nf], 0, 0, 0);
    }
#pragma unroll
    for (int nf = 0; nf < 4; ++nf) {
      const int n = nf * 16 + (lane & 15);
      const float bo = bout[n];
#pragma unroll
      for (int r = 0; r < 4; ++r) {
        const int prow = w * 16 + ((lane >> 4) << 2) + r;
        OUT32[prow * OPAD + n] = ao[nf][r] + bo;
      }
    }
  }
  __syncthreads();

  // phase 5: coalesced residual add + store
  {
    const int r = tid >> 2, rq = tid & 3;
    const size_t gb = (((size_t)b * 512 + i) * 512 + j0 + r) * 64 + rq * 16;
    const float* rr = resid + gb;
    float* op = outp + gb;
#pragma unroll
    for (int u = 0; u < 4; ++u) {
      f32x4 ov = ((const f32x4*)&OUT32[r * OPAD + rq * 16])[u];
      f32x4 rv = ((const f32x4*)rr)[u];
      ((f32x4*)op)[u] = ov + rv;
    }
  }
}

// ---------------------------------------------------------------------------
extern "C" void kernel_launch(void* const* d_in, const int* in_sizes, int n_in,
                              void* d_out, int out_size, void* d_ws, size_t ws_size,
                              hipStream_t stream) {
  const float* x     = (const float*)d_in[0];
  const float* mask  = (const float*)d_in[1];
  const float* lnw1  = (const float*)d_in[2];
  const float* lnb1  = (const float*)d_in[3];
  const float* Wlp   = (const float*)d_in[4];
  const float* blp   = (const float*)d_in[5];
  const float* Wrp   = (const float*)d_in[6];
  const float* brp   = (const float*)d_in[7];
  const float* Wlg   = (const float*)d_in[8];
  const float* blg   = (const float*)d_in[9];
  const float* Wrg   = (const float*)d_in[10];
  const float* brg   = (const float*)d_in[11];
  const float* Wog   = (const float*)d_in[12];
  const float* bog   = (const float*)d_in[13];
  const float* lnw2  = (const float*)d_in[14];
  const float* lnb2  = (const float*)d_in[15];
  const float* Wout  = (const float*)d_in[16];
  const float* bout  = (const float*)d_in[17];

  unsigned short* leftT  = (unsigned short*)d_ws;
  unsigned short* rightT = leftT + (size_t)33554432;
  unsigned short* triT   = rightT + (size_t)33554432;
  unsigned short* wt     = triT + (size_t)33554432;   // 6*64*APAD bf16

  k_prep<<<6, 256, 0, stream>>>(Wlp, Wrp, Wlg, Wrg, Wog, Wout, wt);
  k1_proj<<<8192, 256, 0, stream>>>(x, mask, lnw1, lnb1, blp, brp, blg, brg,
                                    wt, leftT, rightT);
  k2_gemm<<<2048, 256, 0, stream>>>(leftT, rightT, triT);
  k3_out<<<8192, 256, 0, stream>>>(triT, x, lnw1, lnb1, bog, lnw2, lnb2, bout,
                                   wt, (float*)d_out);
}

// Round 4
// 257.744 us; speedup vs baseline: 1.6651x; 1.1892x over previous
//
#include <hip/hip_runtime.h>
#include <cstdint>

typedef float f32x4 __attribute__((ext_vector_type(4)));
typedef short s16x8 __attribute__((ext_vector_type(8)));

#define APAD 72   // padded row (bf16 elems): 144 B rows, 2-way-conflict floor

__device__ __forceinline__ unsigned short f2bf(float f) {
  union { float f; uint32_t u; } v; v.f = f;
  uint32_t u = v.u;
  u += 0x7fffu + ((u >> 16) & 1u);
  return (unsigned short)(u >> 16);
}
__device__ __forceinline__ float bf2f(unsigned short h) {
  union { uint32_t u; float f; } v; v.u = ((uint32_t)h) << 16;
  return v.f;
}
__device__ __forceinline__ float sigmoidf_(float x) {
  return 1.0f / (1.0f + __expf(-x));
}
__device__ __forceinline__ f32x4 zero4() {
  f32x4 z = {0.f, 0.f, 0.f, 0.f};
  return z;
}
__device__ __forceinline__ void gl_lds16(const void* g, void* l) {
  __builtin_amdgcn_global_load_lds(
      (const __attribute__((address_space(1))) uint32_t*)g,
      (__attribute__((address_space(3))) uint32_t*)l, 16, 0, 0);
}

// ---------------------------------------------------------------------------
// prep: transpose 6 weight matrices [k][n] fp32 -> wt bf16 [m][n][APAD]
// ---------------------------------------------------------------------------
__global__ __launch_bounds__(256) void k_prep(
    const float* __restrict__ Wlp, const float* __restrict__ Wrp,
    const float* __restrict__ Wlg, const float* __restrict__ Wrg,
    const float* __restrict__ Wog, const float* __restrict__ Wout,
    unsigned short* __restrict__ wt) {
  const float* srcs[6] = {Wlp, Wrp, Wlg, Wrg, Wog, Wout};
  const int m = blockIdx.x;
  const float* W = srcs[m];
  const int t = threadIdx.x;
  for (int e = t; e < 64 * APAD; e += 256) {
    const int n = e / APAD, k = e - n * APAD;
    wt[m * (64 * APAD) + e] = (k < 64) ? f2bf(W[k * 64 + n]) : (unsigned short)0;
  }
}

// ---------------------------------------------------------------------------
// k1: x = LN(in); left=(x@Wlp+blp)*mask*sig(x@Wlg+blg); right analog.
// Wave w = (pair = w>>1 selects left/right, ch = w&1 selects col half).
// Weights held in VGPRs, loaded once before the barrier.
// ---------------------------------------------------------------------------
__global__ __launch_bounds__(256, 4) void k1_proj(
    const float* __restrict__ xin, const float* __restrict__ mask,
    const float* __restrict__ lnw, const float* __restrict__ lnb,
    const float* __restrict__ blp, const float* __restrict__ brp,
    const float* __restrict__ blg, const float* __restrict__ brg,
    const unsigned short* __restrict__ wt,
    unsigned short* __restrict__ leftT, unsigned short* __restrict__ rightT) {
  __shared__ unsigned short A[64 * APAD];
  __shared__ unsigned short TL[64 * APAD];
  __shared__ unsigned short TR[64 * APAD];
  const int tid = threadIdx.x, lane = tid & 63, w = tid >> 6;
  const int bid = blockIdx.x;
  const int b = bid >> 12;
  const int i = (bid >> 3) & 511;
  const int k0 = (bid & 7) << 6;

  // ---- per-wave weight fragments -> VGPRs (hoisted; hidden under LN) ----
  const int pair = w >> 1, ch = w & 1;
  const int kh8 = (lane >> 4) << 3;
  s16x8 wp[2][2], wg[2][2];
  float bPv[2], bGv[2];
  {
    const unsigned short* wtP = wt + (size_t)pair * (64 * APAD);
    const unsigned short* wtG = wt + (size_t)(2 + pair) * (64 * APAD);
    const float* bP = pair ? brp : blp;
    const float* bG = pair ? brg : blg;
#pragma unroll
    for (int nf2 = 0; nf2 < 2; ++nf2) {
      const int n = ch * 32 + nf2 * 16 + (lane & 15);
      const unsigned short* pp = wtP + n * APAD + kh8;
      const unsigned short* pg = wtG + n * APAD + kh8;
      wp[nf2][0] = *(const s16x8*)pp;  wp[nf2][1] = *(const s16x8*)(pp + 32);
      wg[nf2][0] = *(const s16x8*)pg;  wg[nf2][1] = *(const s16x8*)(pg + 32);
      bPv[nf2] = bP[n];  bGv[nf2] = bG[n];
    }
  }

  // ---- load x rows + layernorm (4 threads per row, 16 ch each) ----
  const int p = tid >> 2, q = tid & 3;
  const float* xrow = xin + (((size_t)b * 512 + i) * 512 + k0 + p) * 64 + q * 16;
  f32x4 xv[4];
#pragma unroll
  for (int u = 0; u < 4; ++u) xv[u] = ((const f32x4*)xrow)[u];
  float s1 = 0.f, s2 = 0.f;
#pragma unroll
  for (int u = 0; u < 4; ++u)
#pragma unroll
    for (int e = 0; e < 4; ++e) { float t = xv[u][e]; s1 += t; s2 += t * t; }
  s1 += __shfl_xor(s1, 1); s2 += __shfl_xor(s2, 1);
  s1 += __shfl_xor(s1, 2); s2 += __shfl_xor(s2, 2);
  const float mu = s1 * 0.015625f;
  const float rs = rsqrtf(s2 * 0.015625f - mu * mu + 1e-5f);
  {
    uint32_t pk[8];
#pragma unroll
    for (int u = 0; u < 4; ++u) {
      f32x4 wv = ((const f32x4*)(lnw + q * 16))[u];
      f32x4 bv = ((const f32x4*)(lnb + q * 16))[u];
#pragma unroll
      for (int e2 = 0; e2 < 2; ++e2) {
        uint32_t lo = f2bf((xv[u][2 * e2] - mu) * rs * wv[2 * e2] + bv[2 * e2]);
        uint32_t hi = f2bf((xv[u][2 * e2 + 1] - mu) * rs * wv[2 * e2 + 1] + bv[2 * e2 + 1]);
        pk[u * 2 + e2] = lo | (hi << 16);
      }
    }
    uint32_t* a32 = (uint32_t*)&A[p * APAD + q * 16];
#pragma unroll
    for (int u = 0; u < 8; ++u) a32[u] = pk[u];
  }
  const float mval = mask[b * 512 + i];
  __syncthreads();

  // ---- MFMA + wave-local combine + transpose ----
  const int fr4 = (lane >> 4) << 2;
  unsigned short* T = pair ? TR : TL;
#pragma unroll
  for (int mf = 0; mf < 4; ++mf) {
    const int ar = (mf * 16 + (lane & 15)) * APAD + kh8;
    const s16x8 a0 = *(const s16x8*)&A[ar];
    const s16x8 a1 = *(const s16x8*)&A[ar + 32];
    f32x4 accP[2], accG[2];
#pragma unroll
    for (int nf2 = 0; nf2 < 2; ++nf2) {
      accP[nf2] = zero4(); accG[nf2] = zero4();
      accP[nf2] = __builtin_amdgcn_mfma_f32_16x16x32_bf16(a0, wp[nf2][0], accP[nf2], 0, 0, 0);
      accP[nf2] = __builtin_amdgcn_mfma_f32_16x16x32_bf16(a1, wp[nf2][1], accP[nf2], 0, 0, 0);
      accG[nf2] = __builtin_amdgcn_mfma_f32_16x16x32_bf16(a0, wg[nf2][0], accG[nf2], 0, 0, 0);
      accG[nf2] = __builtin_amdgcn_mfma_f32_16x16x32_bf16(a1, wg[nf2][1], accG[nf2], 0, 0, 0);
    }
    const int prow = mf * 16 + fr4;
#pragma unroll
    for (int nf2 = 0; nf2 < 2; ++nf2) {
      const int n = ch * 32 + nf2 * 16 + (lane & 15);
      const float bl = bPv[nf2], bg = bGv[nf2];
      float v0 = (accP[nf2][0] + bl) * mval * sigmoidf_(accG[nf2][0] + bg);
      float v1 = (accP[nf2][1] + bl) * mval * sigmoidf_(accG[nf2][1] + bg);
      float v2 = (accP[nf2][2] + bl) * mval * sigmoidf_(accG[nf2][2] + bg);
      float v3 = (accP[nf2][3] + bl) * mval * sigmoidf_(accG[nf2][3] + bg);
      *(uint32_t*)&T[n * APAD + prow] = (uint32_t)f2bf(v0) | ((uint32_t)f2bf(v1) << 16);
      *(uint32_t*)&T[n * APAD + prow + 2] = (uint32_t)f2bf(v2) | ((uint32_t)f2bf(v3) << 16);
    }
  }
  __syncthreads();

  // ---- coalesced stores of both transposed tiles ----
  {
    const int sn = tid >> 2, sq = tid & 3;
    const size_t gbase = (((size_t)b * 64 + sn) * 512 + i) * 512 + k0 + sq * 16;
    const uint32_t* sl = (const uint32_t*)&TL[sn * APAD + sq * 16];
    const uint32_t* sr = (const uint32_t*)&TR[sn * APAD + sq * 16];
    uint32_t* dl = (uint32_t*)(leftT + gbase);
    uint32_t* dr = (uint32_t*)(rightT + gbase);
#pragma unroll
    for (int u = 0; u < 8; ++u) dl[u] = sl[u];
#pragma unroll
    for (int u = 0; u < 8; ++u) dr[u] = sr[u];
  }
}

// ---------------------------------------------------------------------------
// k2: triT[b,c,i,j] = sum_k leftT[b,c,i,k] * rightT[b,c,j,k]
// LDS tiles XOR-swizzled: physical k-slot s_p of row r holds logical slot
// s_p ^ (r&7). Writes stay linear (global_load_lds); the global source per
// lane is pre-permuted; ds_read XORs the same pattern. (T2 / rule #21)
// ---------------------------------------------------------------------------
__global__ __launch_bounds__(256) void k2_gemm(
    const unsigned short* __restrict__ leftT,
    const unsigned short* __restrict__ rightT,
    unsigned short* __restrict__ triT) {
  __shared__ unsigned short Ab[2][128 * 64];
  __shared__ unsigned short Bb[2][128 * 64];
  const int tid = threadIdx.x, lane = tid & 63, w = tid >> 6;
  const int bid = blockIdx.x;
  const int sw = ((bid & 7) << 8) | (bid >> 3);
  const int plane = sw >> 4, tile = sw & 15;
  const size_t pb = (size_t)plane * 262144;
  const int i0 = (tile >> 2) << 7, j0 = (tile & 3) << 7;
  const int srow = lane >> 3;                       // row within 8-row chunk
  const int sk = (((lane & 7) ^ (lane >> 3)) << 3); // pre-swizzled k-slot (elems)

  f32x4 acc[4][4];
#pragma unroll
  for (int mf = 0; mf < 4; ++mf)
#pragma unroll
    for (int nf = 0; nf < 4; ++nf) acc[mf][nf] = zero4();
  const int wr = (w >> 1) << 6, wc = (w & 1) << 6;

  auto stage = [&](int buf, int kt) {
    const int kk = kt << 6;
#pragma unroll
    for (int it = 0; it < 4; ++it) {
      const int ch = it * 4 + w;
      const int row = (ch << 3) + srow;
      gl_lds16(leftT + pb + (size_t)(i0 + row) * 512 + kk + sk,
               (char*)&Ab[buf][0] + ch * 1024 + lane * 16);
      gl_lds16(rightT + pb + (size_t)(j0 + row) * 512 + kk + sk,
               (char*)&Bb[buf][0] + ch * 1024 + lane * 16);
    }
  };

  stage(0, 0);
  for (int kt = 0; kt < 8; ++kt) {
    __syncthreads();
    if (kt < 7) stage((kt & 1) ^ 1, kt + 1);
    const unsigned short* Ac = &Ab[kt & 1][0];
    const unsigned short* Bc = &Bb[kt & 1][0];
#pragma unroll
    for (int ks = 0; ks < 2; ++ks) {
      const int ko = ((lane >> 4) << 3) + (ks << 5);
      const int kosw = ko ^ ((lane & 7) << 3);      // row&7 == lane&7 here
      s16x8 af[4], bfr[4];
#pragma unroll
      for (int mf = 0; mf < 4; ++mf)
        af[mf] = *(const s16x8*)&Ac[(wr + mf * 16 + (lane & 15)) * 64 + kosw];
#pragma unroll
      for (int nf = 0; nf < 4; ++nf)
        bfr[nf] = *(const s16x8*)&Bc[(wc + nf * 16 + (lane & 15)) * 64 + kosw];
#pragma unroll
      for (int mf = 0; mf < 4; ++mf)
#pragma unroll
        for (int nf = 0; nf < 4; ++nf)
          acc[mf][nf] = __builtin_amdgcn_mfma_f32_16x16x32_bf16(af[mf], bfr[nf], acc[mf][nf], 0, 0, 0);
    }
  }
  __syncthreads();
  unsigned short* Tt = &Ab[0][0];
#pragma unroll
  for (int mf = 0; mf < 4; ++mf)
#pragma unroll
    for (int nf = 0; nf < 4; ++nf) {
      const int col = wc + nf * 16 + (lane & 15);
#pragma unroll
      for (int r = 0; r < 4; ++r) {
        const int row = wr + mf * 16 + ((lane >> 4) << 2) + r;
        Tt[row * 128 + col] = f2bf(acc[mf][nf][r]);
      }
    }
  __syncthreads();
  {
    const int row = tid >> 1, half = (tid & 1) << 6;
    const uint32_t* src = (const uint32_t*)&Tt[row * 128 + half];
    uint32_t* dst = (uint32_t*)(triT + pb + (size_t)(i0 + row) * 512 + j0 + half);
#pragma unroll
    for (int u = 0; u < 32; ++u) dst[u] = src[u];
  }
}

// ---------------------------------------------------------------------------
// k3: y = LN_out(tri) * sigmoid(LN_in(resid)@Wog+bog); out = y@Wout+bout+resid
// resid kept in VGPRs across phases (read once). Weights async-staged to LDS.
// ---------------------------------------------------------------------------
#define OPAD 68   // padded f32 out-tile row
__global__ __launch_bounds__(256, 3) void k3_out(
    const unsigned short* __restrict__ triT,
    const float* __restrict__ resid,
    const float* __restrict__ lnw1, const float* __restrict__ lnb1,
    const float* __restrict__ bog,
    const float* __restrict__ lnw2, const float* __restrict__ lnb2,
    const float* __restrict__ bout,
    const unsigned short* __restrict__ wt,
    float* __restrict__ outp) {
  __shared__ __align__(16) unsigned char smem[18432 + 27648];
  unsigned short* WT = (unsigned short*)smem;                     // [2][64][APAD]
  unsigned short* Y  = (unsigned short*)(smem + 18432);           // [64][APAD]
  unsigned short* X  = (unsigned short*)(smem + 18432 + 9216);    // [64][APAD]
  unsigned short* OG = (unsigned short*)(smem + 18432 + 18432);   // [64][APAD]
  float* OUT32 = (float*)(smem + 18432 + 9216);                   // aliases X,OG
  const int tid = threadIdx.x, lane = tid & 63, w = tid >> 6;
  const int bid = blockIdx.x;
  const int b = bid >> 12;
  const int i = (bid >> 3) & 511;
  const int j0 = (bid & 7) << 6;

  // async-stage og^T and out^T (18432 B), overlapped with phase 1
  const char* wsrc = (const char*)(wt + (size_t)4 * (64 * APAD));
#pragma unroll
  for (int it = 0; it < 5; ++it) {
    const int off = (it * 256 + tid) * 16;
    if (off < 18432) gl_lds16(wsrc + off, (char*)WT + off);
  }

  const int j = tid >> 2, q = tid & 3;
  // phase 1: tri tile -> transposed Y[j][c]; resid LN -> X (resid kept in rv)
  {
    const int c = tid >> 2;
    const size_t srow = ((size_t)(b * 64 + c) * 512 + i) * 512 + j0 + q * 16;
    union { uint32_t u32[8]; unsigned short s[16]; } uu;
    const uint32_t* s32 = (const uint32_t*)(triT + srow);
#pragma unroll
    for (int u = 0; u < 8; ++u) uu.u32[u] = s32[u];
#pragma unroll
    for (int s = 0; s < 16; ++s) Y[(q * 16 + s) * APAD + c] = uu.s[s];
  }
  f32x4 rv[4];   // resid row fragment, reused in phase 5
  {
    const float* rrow = resid + (((size_t)b * 512 + i) * 512 + j0 + j) * 64 + q * 16;
#pragma unroll
    for (int u = 0; u < 4; ++u) rv[u] = ((const f32x4*)rrow)[u];
    float s1 = 0.f, s2 = 0.f;
#pragma unroll
    for (int u = 0; u < 4; ++u)
#pragma unroll
      for (int e = 0; e < 4; ++e) { float t = rv[u][e]; s1 += t; s2 += t * t; }
    s1 += __shfl_xor(s1, 1); s2 += __shfl_xor(s2, 1);
    s1 += __shfl_xor(s1, 2); s2 += __shfl_xor(s2, 2);
    const float mu = s1 * 0.015625f;
    const float rs = rsqrtf(s2 * 0.015625f - mu * mu + 1e-5f);
    uint32_t pk[8];
#pragma unroll
    for (int u = 0; u < 4; ++u) {
      f32x4 wv = ((const f32x4*)(lnw1 + q * 16))[u];
      f32x4 bv = ((const f32x4*)(lnb1 + q * 16))[u];
#pragma unroll
      for (int e2 = 0; e2 < 2; ++e2) {
        uint32_t lo = f2bf((rv[u][2 * e2] - mu) * rs * wv[2 * e2] + bv[2 * e2]);
        uint32_t hi = f2bf((rv[u][2 * e2 + 1] - mu) * rs * wv[2 * e2 + 1] + bv[2 * e2 + 1]);
        pk[u * 2 + e2] = lo | (hi << 16);
      }
    }
    uint32_t* x32 = (uint32_t*)&X[j * APAD + q * 16];
#pragma unroll
    for (int u = 0; u < 8; ++u) x32[u] = pk[u];
  }
  __syncthreads();

  // phase 2: tri LN stats (regs) + og MFMA
  float yv[16];
  {
    union { uint32_t u32[8]; unsigned short s[16]; } uy;
    const uint32_t* y32 = (const uint32_t*)&Y[j * APAD + q * 16];
#pragma unroll
    for (int u = 0; u < 8; ++u) uy.u32[u] = y32[u];
#pragma unroll
    for (int s = 0; s < 16; ++s) yv[s] = bf2f(uy.s[s]);
  }
  float t1 = 0.f, t2 = 0.f;
#pragma unroll
  for (int s = 0; s < 16; ++s) { t1 += yv[s]; t2 += yv[s] * yv[s]; }
  t1 += __shfl_xor(t1, 1); t2 += __shfl_xor(t2, 1);
  t1 += __shfl_xor(t1, 2); t2 += __shfl_xor(t2, 2);
  const float mu2 = t1 * 0.015625f;
  const float rs2 = rsqrtf(t2 * 0.015625f - mu2 * mu2 + 1e-5f);

  const int arow = (w * 16 + (lane & 15)) * APAD + ((lane >> 4) << 3);
  {
    const s16x8 a0 = *(const s16x8*)&X[arow];
    const s16x8 a1 = *(const s16x8*)&X[arow + 32];
    f32x4 aog[4];
#pragma unroll
    for (int nf = 0; nf < 4; ++nf) aog[nf] = zero4();
#pragma unroll
    for (int nf = 0; nf < 4; ++nf) {
      const int brow = (nf * 16 + (lane & 15)) * APAD + ((lane >> 4) << 3);
      const s16x8 b0 = *(const s16x8*)&WT[brow];
      const s16x8 b1 = *(const s16x8*)&WT[brow + 32];
      aog[nf] = __builtin_amdgcn_mfma_f32_16x16x32_bf16(a0, b0, aog[nf], 0, 0, 0);
      aog[nf] = __builtin_amdgcn_mfma_f32_16x16x32_bf16(a1, b1, aog[nf], 0, 0, 0);
    }
#pragma unroll
    for (int nf = 0; nf < 4; ++nf) {
      const int n = nf * 16 + (lane & 15);
      const float bb = bog[n];
#pragma unroll
      for (int r = 0; r < 4; ++r) {
        const int prow = w * 16 + ((lane >> 4) << 2) + r;
        OG[prow * APAD + n] = f2bf(sigmoidf_(aog[nf][r] + bb));
      }
    }
  }
  __syncthreads();

  // phase 3: y = LN_out(tri) * og -> Y bf16
  {
    union { uint32_t u32[8]; unsigned short s[16]; } og_;
    const uint32_t* o32 = (const uint32_t*)&OG[j * APAD + q * 16];
#pragma unroll
    for (int u = 0; u < 8; ++u) og_.u32[u] = o32[u];
    uint32_t pk[8];
#pragma unroll
    for (int u = 0; u < 4; ++u) {
      f32x4 wv = ((const f32x4*)(lnw2 + q * 16))[u];
      f32x4 bv = ((const f32x4*)(lnb2 + q * 16))[u];
#pragma unroll
      for (int e2 = 0; e2 < 2; ++e2) {
        const int s0 = u * 4 + 2 * e2;
        float y0 = ((yv[s0] - mu2) * rs2 * wv[2 * e2] + bv[2 * e2]) * bf2f(og_.s[s0]);
        float y1 = ((yv[s0 + 1] - mu2) * rs2 * wv[2 * e2 + 1] + bv[2 * e2 + 1]) * bf2f(og_.s[s0 + 1]);
        pk[u * 2 + e2] = (uint32_t)f2bf(y0) | ((uint32_t)f2bf(y1) << 16);
      }
    }
    uint32_t* y32 = (uint32_t*)&Y[j * APAD + q * 16];
#pragma unroll
    for (int u = 0; u < 8; ++u) y32[u] = pk[u];
  }
  __syncthreads();

  // phase 4: out = Y @ Wout + bout -> OUT32 (LDS, padded)
  {
    const s16x8 a0 = *(const s16x8*)&Y[arow];
    const s16x8 a1 = *(const s16x8*)&Y[arow + 32];
    f32x4 ao[4];
#pragma unroll
    for (int nf = 0; nf < 4; ++nf) ao[nf] = zero4();
#pragma unroll
    for (int nf = 0; nf < 4; ++nf) {
      const int brow = 64 * APAD + (nf * 16 + (lane & 15)) * APAD + ((lane >> 4) << 3);
      const s16x8 b0 = *(const s16x8*)&WT[brow];
      const s16x8 b1 = *(const s16x8*)&WT[brow + 32];
      ao[nf] = __builtin_amdgcn_mfma_f32_16x16x32_bf16(a0, b0, ao[nf], 0, 0, 0);
      ao[nf] = __builtin_amdgcn_mfma_f32_16x16x32_bf16(a1, b1, ao[nf], 0, 0, 0);
    }
#pragma unroll
    for (int nf = 0; nf < 4; ++nf) {
      const int n = nf * 16 + (lane & 15);
      const float bo = bout[n];
#pragma unroll
      for (int r = 0; r < 4; ++r) {
        const int prow = w * 16 + ((lane >> 4) << 2) + r;
        OUT32[prow * OPAD + n] = ao[nf][r] + bo;
      }
    }
  }
  __syncthreads();

  // phase 5: coalesced residual add (resid from regs) + store
  {
    const size_t gb = (((size_t)b * 512 + i) * 512 + j0 + j) * 64 + q * 16;
    float* op = outp + gb;
#pragma unroll
    for (int u = 0; u < 4; ++u) {
      f32x4 ov = ((const f32x4*)&OUT32[j * OPAD + q * 16])[u];
      ((f32x4*)op)[u] = ov + rv[u];
    }
  }
}

// ---------------------------------------------------------------------------
extern "C" void kernel_launch(void* const* d_in, const int* in_sizes, int n_in,
                              void* d_out, int out_size, void* d_ws, size_t ws_size,
                              hipStream_t stream) {
  const float* x     = (const float*)d_in[0];
  const float* mask  = (const float*)d_in[1];
  const float* lnw1  = (const float*)d_in[2];
  const float* lnb1  = (const float*)d_in[3];
  const float* Wlp   = (const float*)d_in[4];
  const float* blp   = (const float*)d_in[5];
  const float* Wrp   = (const float*)d_in[6];
  const float* brp   = (const float*)d_in[7];
  const float* Wlg   = (const float*)d_in[8];
  const float* blg   = (const float*)d_in[9];
  const float* Wrg   = (const float*)d_in[10];
  const float* brg   = (const float*)d_in[11];
  const float* Wog   = (const float*)d_in[12];
  const float* bog   = (const float*)d_in[13];
  const float* lnw2  = (const float*)d_in[14];
  const float* lnb2  = (const float*)d_in[15];
  const float* Wout  = (const float*)d_in[16];
  const float* bout  = (const float*)d_in[17];

  unsigned short* leftT  = (unsigned short*)d_ws;
  unsigned short* rightT = leftT + (size_t)33554432;
  unsigned short* triT   = rightT + (size_t)33554432;
  unsigned short* wt     = triT + (size_t)33554432;   // 6*64*APAD bf16

  k_prep<<<6, 256, 0, stream>>>(Wlp, Wrp, Wlg, Wrg, Wog, Wout, wt);
  k1_proj<<<8192, 256, 0, stream>>>(x, mask, lnw1, lnb1, blp, brp, blg, brg,
                                    wt, leftT, rightT);
  k2_gemm<<<2048, 256, 0, stream>>>(leftT, rightT, triT);
  k3_out<<<8192, 256, 0, stream>>>(triT, x, lnw1, lnb1, bog, lnw2, lnb2, bout,
                                   wt, (float*)d_out);
}

// Round 5
// 249.458 us; speedup vs baseline: 1.7204x; 1.0332x over previous
//
#include <hip/hip_runtime.h>
#include <cstdint>

typedef float f32x4 __attribute__((ext_vector_type(4)));
typedef short s16x8 __attribute__((ext_vector_type(8)));

#define APAD 72   // padded row (bf16 elems): 144 B rows, 2-way-conflict floor

__device__ __forceinline__ unsigned short f2bf(float f) {
  union { float f; uint32_t u; } v; v.f = f;
  uint32_t u = v.u;
  u += 0x7fffu + ((u >> 16) & 1u);
  return (unsigned short)(u >> 16);
}
__device__ __forceinline__ float bf2f(unsigned short h) {
  union { uint32_t u; float f; } v; v.u = ((uint32_t)h) << 16;
  return v.f;
}
// packed f32x2 -> bf16x2 (lo = a, hi = b), single VALU op
__device__ __forceinline__ uint32_t pkbf(float a, float b) {
  uint32_t r;
  asm("v_cvt_pk_bf16_f32 %0, %1, %2" : "=v"(r) : "v"(a), "v"(b));
  return r;
}
__device__ __forceinline__ float sigmoidf_(float x) {
  return 1.0f / (1.0f + __expf(-x));
}
__device__ __forceinline__ f32x4 zero4() {
  f32x4 z = {0.f, 0.f, 0.f, 0.f};
  return z;
}
__device__ __forceinline__ void gl_lds16(const void* g, void* l) {
  __builtin_amdgcn_global_load_lds(
      (const __attribute__((address_space(1))) uint32_t*)g,
      (__attribute__((address_space(3))) uint32_t*)l, 16, 0, 0);
}

// ---------------------------------------------------------------------------
// prep: transpose 6 weight matrices [k][n] fp32 -> wt bf16 [m][n][APAD]
// ---------------------------------------------------------------------------
__global__ __launch_bounds__(256) void k_prep(
    const float* __restrict__ Wlp, const float* __restrict__ Wrp,
    const float* __restrict__ Wlg, const float* __restrict__ Wrg,
    const float* __restrict__ Wog, const float* __restrict__ Wout,
    unsigned short* __restrict__ wt) {
  const float* srcs[6] = {Wlp, Wrp, Wlg, Wrg, Wog, Wout};
  const int m = blockIdx.x;
  const float* W = srcs[m];
  const int t = threadIdx.x;
  for (int e = t; e < 64 * APAD; e += 256) {
    const int n = e / APAD, k = e - n * APAD;
    wt[m * (64 * APAD) + e] = (k < 64) ? f2bf(W[k * 64 + n]) : (unsigned short)0;
  }
}

// ---------------------------------------------------------------------------
// k1: x = LN(in); left=(x@Wlp+blp)*mask*sig(x@Wlg+blg); right analog.
// Wave w = (pair = w>>1 selects left/right, ch = w&1 selects col half).
// Weights held in VGPRs, loaded once before the barrier.
// ---------------------------------------------------------------------------
__global__ __launch_bounds__(256, 4) void k1_proj(
    const float* __restrict__ xin, const float* __restrict__ mask,
    const float* __restrict__ lnw, const float* __restrict__ lnb,
    const float* __restrict__ blp, const float* __restrict__ brp,
    const float* __restrict__ blg, const float* __restrict__ brg,
    const unsigned short* __restrict__ wt,
    unsigned short* __restrict__ leftT, unsigned short* __restrict__ rightT) {
  __shared__ unsigned short A[64 * APAD];
  __shared__ unsigned short TL[64 * APAD];
  __shared__ unsigned short TR[64 * APAD];
  const int tid = threadIdx.x, lane = tid & 63, w = tid >> 6;
  const int bid = blockIdx.x;
  const int b = bid >> 12;
  const int i = (bid >> 3) & 511;
  const int k0 = (bid & 7) << 6;

  // ---- per-wave weight fragments -> VGPRs (hoisted; hidden under LN) ----
  const int pair = w >> 1, ch = w & 1;
  const int kh8 = (lane >> 4) << 3;
  s16x8 wp[2][2], wg[2][2];
  float bPv[2], bGv[2];
  {
    const unsigned short* wtP = wt + (size_t)pair * (64 * APAD);
    const unsigned short* wtG = wt + (size_t)(2 + pair) * (64 * APAD);
    const float* bP = pair ? brp : blp;
    const float* bG = pair ? brg : blg;
#pragma unroll
    for (int nf2 = 0; nf2 < 2; ++nf2) {
      const int n = ch * 32 + nf2 * 16 + (lane & 15);
      const unsigned short* pp = wtP + n * APAD + kh8;
      const unsigned short* pg = wtG + n * APAD + kh8;
      wp[nf2][0] = *(const s16x8*)pp;  wp[nf2][1] = *(const s16x8*)(pp + 32);
      wg[nf2][0] = *(const s16x8*)pg;  wg[nf2][1] = *(const s16x8*)(pg + 32);
      bPv[nf2] = bP[n];  bGv[nf2] = bG[n];
    }
  }

  // ---- load x rows + layernorm (4 threads per row, 16 ch each) ----
  const int p = tid >> 2, q = tid & 3;
  const float* xrow = xin + (((size_t)b * 512 + i) * 512 + k0 + p) * 64 + q * 16;
  f32x4 xv[4];
#pragma unroll
  for (int u = 0; u < 4; ++u) xv[u] = ((const f32x4*)xrow)[u];
  float s1 = 0.f, s2 = 0.f;
#pragma unroll
  for (int u = 0; u < 4; ++u)
#pragma unroll
    for (int e = 0; e < 4; ++e) { float t = xv[u][e]; s1 += t; s2 += t * t; }
  s1 += __shfl_xor(s1, 1); s2 += __shfl_xor(s2, 1);
  s1 += __shfl_xor(s1, 2); s2 += __shfl_xor(s2, 2);
  const float mu = s1 * 0.015625f;
  const float rs = rsqrtf(s2 * 0.015625f - mu * mu + 1e-5f);
  {
    uint32_t pk[8];
#pragma unroll
    for (int u = 0; u < 4; ++u) {
      f32x4 wv = ((const f32x4*)(lnw + q * 16))[u];
      f32x4 bv = ((const f32x4*)(lnb + q * 16))[u];
#pragma unroll
      for (int e2 = 0; e2 < 2; ++e2) {
        pk[u * 2 + e2] = pkbf((xv[u][2 * e2] - mu) * rs * wv[2 * e2] + bv[2 * e2],
                              (xv[u][2 * e2 + 1] - mu) * rs * wv[2 * e2 + 1] + bv[2 * e2 + 1]);
      }
    }
    uint32_t* a32 = (uint32_t*)&A[p * APAD + q * 16];
#pragma unroll
    for (int u = 0; u < 8; ++u) a32[u] = pk[u];
  }
  const float mval = mask[b * 512 + i];
  __syncthreads();

  // ---- MFMA + wave-local combine + transpose ----
  const int fr4 = (lane >> 4) << 2;
  unsigned short* T = pair ? TR : TL;
#pragma unroll
  for (int mf = 0; mf < 4; ++mf) {
    const int ar = (mf * 16 + (lane & 15)) * APAD + kh8;
    const s16x8 a0 = *(const s16x8*)&A[ar];
    const s16x8 a1 = *(const s16x8*)&A[ar + 32];
    f32x4 accP[2], accG[2];
#pragma unroll
    for (int nf2 = 0; nf2 < 2; ++nf2) {
      accP[nf2] = zero4(); accG[nf2] = zero4();
      accP[nf2] = __builtin_amdgcn_mfma_f32_16x16x32_bf16(a0, wp[nf2][0], accP[nf2], 0, 0, 0);
      accP[nf2] = __builtin_amdgcn_mfma_f32_16x16x32_bf16(a1, wp[nf2][1], accP[nf2], 0, 0, 0);
      accG[nf2] = __builtin_amdgcn_mfma_f32_16x16x32_bf16(a0, wg[nf2][0], accG[nf2], 0, 0, 0);
      accG[nf2] = __builtin_amdgcn_mfma_f32_16x16x32_bf16(a1, wg[nf2][1], accG[nf2], 0, 0, 0);
    }
    const int prow = mf * 16 + fr4;
#pragma unroll
    for (int nf2 = 0; nf2 < 2; ++nf2) {
      const int n = ch * 32 + nf2 * 16 + (lane & 15);
      const float bl = bPv[nf2], bg = bGv[nf2];
      float v0 = (accP[nf2][0] + bl) * mval * sigmoidf_(accG[nf2][0] + bg);
      float v1 = (accP[nf2][1] + bl) * mval * sigmoidf_(accG[nf2][1] + bg);
      float v2 = (accP[nf2][2] + bl) * mval * sigmoidf_(accG[nf2][2] + bg);
      float v3 = (accP[nf2][3] + bl) * mval * sigmoidf_(accG[nf2][3] + bg);
      *(uint32_t*)&T[n * APAD + prow] = pkbf(v0, v1);
      *(uint32_t*)&T[n * APAD + prow + 2] = pkbf(v2, v3);
    }
  }
  __syncthreads();

  // ---- coalesced stores of both transposed tiles ----
  {
    const int sn = tid >> 2, sq = tid & 3;
    const size_t gbase = (((size_t)b * 64 + sn) * 512 + i) * 512 + k0 + sq * 16;
    const uint32_t* sl = (const uint32_t*)&TL[sn * APAD + sq * 16];
    const uint32_t* sr = (const uint32_t*)&TR[sn * APAD + sq * 16];
    uint32_t* dl = (uint32_t*)(leftT + gbase);
    uint32_t* dr = (uint32_t*)(rightT + gbase);
#pragma unroll
    for (int u = 0; u < 8; ++u) dl[u] = sl[u];
#pragma unroll
    for (int u = 0; u < 8; ++u) dr[u] = sr[u];
  }
}

// ---------------------------------------------------------------------------
// k2: triT[b,c,i,j] = sum_k leftT[b,c,i,k] * rightT[b,c,j,k]
// LDS XOR-swizzled (T2 / rule #21): linear dest + pre-swizzled source + XOR read.
// ---------------------------------------------------------------------------
__global__ __launch_bounds__(256) void k2_gemm(
    const unsigned short* __restrict__ leftT,
    const unsigned short* __restrict__ rightT,
    unsigned short* __restrict__ triT) {
  __shared__ unsigned short Ab[2][128 * 64];
  __shared__ unsigned short Bb[2][128 * 64];
  const int tid = threadIdx.x, lane = tid & 63, w = tid >> 6;
  const int bid = blockIdx.x;
  const int sw = ((bid & 7) << 8) | (bid >> 3);
  const int plane = sw >> 4, tile = sw & 15;
  const size_t pb = (size_t)plane * 262144;
  const int i0 = (tile >> 2) << 7, j0 = (tile & 3) << 7;
  const int srow = lane >> 3;
  const int sk = (((lane & 7) ^ (lane >> 3)) << 3);

  f32x4 acc[4][4];
#pragma unroll
  for (int mf = 0; mf < 4; ++mf)
#pragma unroll
    for (int nf = 0; nf < 4; ++nf) acc[mf][nf] = zero4();
  const int wr = (w >> 1) << 6, wc = (w & 1) << 6;

  auto stage = [&](int buf, int kt) {
    const int kk = kt << 6;
#pragma unroll
    for (int it = 0; it < 4; ++it) {
      const int ch = it * 4 + w;
      const int row = (ch << 3) + srow;
      gl_lds16(leftT + pb + (size_t)(i0 + row) * 512 + kk + sk,
               (char*)&Ab[buf][0] + ch * 1024 + lane * 16);
      gl_lds16(rightT + pb + (size_t)(j0 + row) * 512 + kk + sk,
               (char*)&Bb[buf][0] + ch * 1024 + lane * 16);
    }
  };

  stage(0, 0);
  for (int kt = 0; kt < 8; ++kt) {
    __syncthreads();
    if (kt < 7) stage((kt & 1) ^ 1, kt + 1);
    const unsigned short* Ac = &Ab[kt & 1][0];
    const unsigned short* Bc = &Bb[kt & 1][0];
#pragma unroll
    for (int ks = 0; ks < 2; ++ks) {
      const int ko = ((lane >> 4) << 3) + (ks << 5);
      const int kosw = ko ^ ((lane & 7) << 3);
      s16x8 af[4], bfr[4];
#pragma unroll
      for (int mf = 0; mf < 4; ++mf)
        af[mf] = *(const s16x8*)&Ac[(wr + mf * 16 + (lane & 15)) * 64 + kosw];
#pragma unroll
      for (int nf = 0; nf < 4; ++nf)
        bfr[nf] = *(const s16x8*)&Bc[(wc + nf * 16 + (lane & 15)) * 64 + kosw];
#pragma unroll
      for (int mf = 0; mf < 4; ++mf)
#pragma unroll
        for (int nf = 0; nf < 4; ++nf)
          acc[mf][nf] = __builtin_amdgcn_mfma_f32_16x16x32_bf16(af[mf], bfr[nf], acc[mf][nf], 0, 0, 0);
    }
  }
  __syncthreads();
  unsigned short* Tt = &Ab[0][0];
#pragma unroll
  for (int mf = 0; mf < 4; ++mf)
#pragma unroll
    for (int nf = 0; nf < 4; ++nf) {
      const int col = wc + nf * 16 + (lane & 15);
#pragma unroll
      for (int r = 0; r < 4; ++r) {
        const int row = wr + mf * 16 + ((lane >> 4) << 2) + r;
        Tt[row * 128 + col] = f2bf(acc[mf][nf][r]);
      }
    }
  __syncthreads();
  {
    const int row = tid >> 1, half = (tid & 1) << 6;
    const uint32_t* src = (const uint32_t*)&Tt[row * 128 + half];
    uint32_t* dst = (uint32_t*)(triT + pb + (size_t)(i0 + row) * 512 + j0 + half);
#pragma unroll
    for (int u = 0; u < 32; ++u) dst[u] = src[u];
  }
}

// ---------------------------------------------------------------------------
// k3: y = LN_out(tri) * sigmoid(LN_in(resid)@Wog+bog); out = y@Wout+bout+resid
// Y tile c-index XOR-swizzled by ((j>>4)&3)<<4: lane-varying in the phase-1
// scatter (kills 8-way conflicts), wave-uniform in phases 2-4 (free reads).
// og-MFMA swapped (D=Wog^T*X) so lane holds adjacent c-pairs -> cvt_pk stores.
// Wout staged late into the dead Wog LDS region -> 36.9 KB, 4 blocks/CU.
// ---------------------------------------------------------------------------
#define OPAD 68   // padded f32 out-tile row
__global__ __launch_bounds__(256, 4) void k3_out(
    const unsigned short* __restrict__ triT,
    const float* __restrict__ resid,
    const float* __restrict__ lnw1, const float* __restrict__ lnb1,
    const float* __restrict__ bog,
    const float* __restrict__ lnw2, const float* __restrict__ lnb2,
    const float* __restrict__ bout,
    const unsigned short* __restrict__ wt,
    float* __restrict__ outp) {
  __shared__ __align__(16) unsigned char smem[36864];
  unsigned short* WT = (unsigned short*)smem;             // [64][APAD] og^T, then out^T
  unsigned short* Y  = (unsigned short*)(smem + 9216);    // [64][APAD] bf16 (swizzled c)
  unsigned short* X  = (unsigned short*)(smem + 18432);   // [64][APAD] bf16
  unsigned short* OG = (unsigned short*)(smem + 27648);   // [64][APAD] bf16
  float* OUT32 = (float*)(smem + 18432);                  // [64][OPAD] f32 (aliases X,OG)
  const int tid = threadIdx.x, lane = tid & 63, w = tid >> 6;
  const int bid = blockIdx.x;
  const int b = bid >> 12;
  const int i = (bid >> 3) & 511;
  const int j0 = (bid & 7) << 6;

  // async-stage og^T (9216 B), overlapped with phase 1
  {
    const char* wsrc = (const char*)(wt + (size_t)4 * (64 * APAD));
#pragma unroll
    for (int it = 0; it < 3; ++it) {
      const int off = (it * 256 + tid) * 16;
      if (off < 9216) gl_lds16(wsrc + off, (char*)WT + off);
    }
  }

  const int j = tid >> 2, q = tid & 3;
  // phase 1: tri tile -> transposed Y[j][c^swz] ; resid LN -> X
  {
    const int c = tid >> 2;
    const int csw = c ^ (q << 4);        // swizzle value = j>>4 = q here
    const size_t srow = ((size_t)(b * 64 + c) * 512 + i) * 512 + j0 + q * 16;
    union { uint32_t u32[8]; unsigned short s[16]; } uu;
    const uint32_t* s32 = (const uint32_t*)(triT + srow);
#pragma unroll
    for (int u = 0; u < 8; ++u) uu.u32[u] = s32[u];
#pragma unroll
    for (int s = 0; s < 16; ++s) Y[(q * 16 + s) * APAD + csw] = uu.s[s];
  }
  f32x4 rv[4];   // resid row fragment, reused in phase 5
  {
    const float* rrow = resid + (((size_t)b * 512 + i) * 512 + j0 + j) * 64 + q * 16;
#pragma unroll
    for (int u = 0; u < 4; ++u) rv[u] = ((const f32x4*)rrow)[u];
    float s1 = 0.f, s2 = 0.f;
#pragma unroll
    for (int u = 0; u < 4; ++u)
#pragma unroll
      for (int e = 0; e < 4; ++e) { float t = rv[u][e]; s1 += t; s2 += t * t; }
    s1 += __shfl_xor(s1, 1); s2 += __shfl_xor(s2, 1);
    s1 += __shfl_xor(s1, 2); s2 += __shfl_xor(s2, 2);
    const float mu = s1 * 0.015625f;
    const float rs = rsqrtf(s2 * 0.015625f - mu * mu + 1e-5f);
    uint32_t pk[8];
#pragma unroll
    for (int u = 0; u < 4; ++u) {
      f32x4 wv = ((const f32x4*)(lnw1 + q * 16))[u];
      f32x4 bv = ((const f32x4*)(lnb1 + q * 16))[u];
#pragma unroll
      for (int e2 = 0; e2 < 2; ++e2) {
        pk[u * 2 + e2] = pkbf((rv[u][2 * e2] - mu) * rs * wv[2 * e2] + bv[2 * e2],
                              (rv[u][2 * e2 + 1] - mu) * rs * wv[2 * e2 + 1] + bv[2 * e2 + 1]);
      }
    }
    uint32_t* x32 = (uint32_t*)&X[j * APAD + q * 16];
#pragma unroll
    for (int u = 0; u < 8; ++u) x32[u] = pk[u];
  }
  __syncthreads();

  // phase 2: tri LN stats (regs) + swapped og MFMA
  const int qx = q ^ (w & 3);            // physical chunk of logical chunk q
  float yv[16];
  {
    union { uint32_t u32[8]; unsigned short s[16]; } uy;
    const uint32_t* y32 = (const uint32_t*)&Y[j * APAD + (qx << 4)];
#pragma unroll
    for (int u = 0; u < 8; ++u) uy.u32[u] = y32[u];
#pragma unroll
    for (int s = 0; s < 16; ++s) yv[s] = bf2f(uy.s[s]);
  }
  float t1 = 0.f, t2 = 0.f;
#pragma unroll
  for (int s = 0; s < 16; ++s) { t1 += yv[s]; t2 += yv[s] * yv[s]; }
  t1 += __shfl_xor(t1, 1); t2 += __shfl_xor(t2, 1);
  t1 += __shfl_xor(t1, 2); t2 += __shfl_xor(t2, 2);
  const float mu2 = t1 * 0.015625f;
  const float rs2 = rsqrtf(t2 * 0.015625f - mu2 * mu2 + 1e-5f);

  const int kh8 = (lane >> 4) << 3;
  {
    // B-operand: X rows j = w*16 + (lane&15), k contiguous
    const int xrow = (w * 16 + (lane & 15)) * APAD;
    const s16x8 xb0 = *(const s16x8*)&X[xrow + kh8];
    const s16x8 xb1 = *(const s16x8*)&X[xrow + kh8 + 32];
    const int jcol = w * 16 + (lane & 15);
    uint32_t* og32 = (uint32_t*)&OG[jcol * APAD];
#pragma unroll
    for (int nf = 0; nf < 4; ++nf) {
      const int wrow = (nf * 16 + (lane & 15)) * APAD;
      const s16x8 wa0 = *(const s16x8*)&WT[wrow + kh8];
      const s16x8 wa1 = *(const s16x8*)&WT[wrow + kh8 + 32];
      f32x4 aog = zero4();
      aog = __builtin_amdgcn_mfma_f32_16x16x32_bf16(wa0, xb0, aog, 0, 0, 0);
      aog = __builtin_amdgcn_mfma_f32_16x16x32_bf16(wa1, xb1, aog, 0, 0, 0);
      // D: col = j (lane&15), rows c = (lane>>4)*4 + r + 16*nf  (adjacent pairs!)
      const f32x4 bb4 = ((const f32x4*)bog)[(lane >> 4) + 4 * nf];
      const float s0 = sigmoidf_(aog[0] + bb4[0]);
      const float s1_ = sigmoidf_(aog[1] + bb4[1]);
      const float s2_ = sigmoidf_(aog[2] + bb4[2]);
      const float s3 = sigmoidf_(aog[3] + bb4[3]);
      const int c2 = (lane >> 4) * 2 + nf * 8;
      og32[c2] = pkbf(s0, s1_);
      og32[c2 + 1] = pkbf(s2_, s3);
    }
  }
  __syncthreads();

  // late-stage out^T into the (now dead) og weight region, hidden under p3
  {
    const char* wsrc2 = (const char*)(wt + (size_t)5 * (64 * APAD));
#pragma unroll
    for (int it = 0; it < 3; ++it) {
      const int off = (it * 256 + tid) * 16;
      if (off < 9216) gl_lds16(wsrc2 + off, (char*)WT + off);
    }
  }

  // phase 3: y = LN_out(tri) * og -> Y bf16 (same swizzled chunk)
  {
    union { uint32_t u32[8]; unsigned short s[16]; } og_;
    const uint32_t* o32 = (const uint32_t*)&OG[j * APAD + q * 16];
#pragma unroll
    for (int u = 0; u < 8; ++u) og_.u32[u] = o32[u];
    uint32_t pk[8];
#pragma unroll
    for (int u = 0; u < 4; ++u) {
      f32x4 wv = ((const f32x4*)(lnw2 + q * 16))[u];
      f32x4 bv = ((const f32x4*)(lnb2 + q * 16))[u];
#pragma unroll
      for (int e2 = 0; e2 < 2; ++e2) {
        const int s0 = u * 4 + 2 * e2;
        float y0 = ((yv[s0] - mu2) * rs2 * wv[2 * e2] + bv[2 * e2]) * bf2f(og_.s[s0]);
        float y1 = ((yv[s0 + 1] - mu2) * rs2 * wv[2 * e2 + 1] + bv[2 * e2 + 1]) * bf2f(og_.s[s0 + 1]);
        pk[u * 2 + e2] = pkbf(y0, y1);
      }
    }
    uint32_t* y32 = (uint32_t*)&Y[j * APAD + (qx << 4)];
#pragma unroll
    for (int u = 0; u < 8; ++u) y32[u] = pk[u];
  }
  __syncthreads();

  // phase 4: out = Y @ Wout + bout -> OUT32 (LDS, padded)
  {
    const int xsw = (w & 3) << 4;
    const int arow = (w * 16 + (lane & 15)) * APAD;
    const s16x8 a0 = *(const s16x8*)&Y[arow + (kh8 ^ xsw)];
    const s16x8 a1 = *(const s16x8*)&Y[arow + ((32 + kh8) ^ xsw)];
    f32x4 ao[4];
#pragma unroll
    for (int nf = 0; nf < 4; ++nf) ao[nf] = zero4();
#pragma unroll
    for (int nf = 0; nf < 4; ++nf) {
      const int brow = (nf * 16 + (lane & 15)) * APAD + kh8;
      const s16x8 b0 = *(const s16x8*)&WT[brow];
      const s16x8 b1 = *(const s16x8*)&WT[brow + 32];
      ao[nf] = __builtin_amdgcn_mfma_f32_16x16x32_bf16(a0, b0, ao[nf], 0, 0, 0);
      ao[nf] = __builtin_amdgcn_mfma_f32_16x16x32_bf16(a1, b1, ao[nf], 0, 0, 0);
    }
#pragma unroll
    for (int nf = 0; nf < 4; ++nf) {
      const int n = nf * 16 + (lane & 15);
      const float bo = bout[n];
#pragma unroll
      for (int r = 0; r < 4; ++r) {
        const int prow = w * 16 + ((lane >> 4) << 2) + r;
        OUT32[prow * OPAD + n] = ao[nf][r] + bo;
      }
    }
  }
  __syncthreads();

  // phase 5: coalesced residual add (resid from regs) + store
  {
    const size_t gb = (((size_t)b * 512 + i) * 512 + j0 + j) * 64 + q * 16;
    float* op = outp + gb;
#pragma unroll
    for (int u = 0; u < 4; ++u) {
      f32x4 ov = ((const f32x4*)&OUT32[j * OPAD + q * 16])[u];
      ((f32x4*)op)[u] = ov + rv[u];
    }
  }
}

// ---------------------------------------------------------------------------
extern "C" void kernel_launch(void* const* d_in, const int* in_sizes, int n_in,
                              void* d_out, int out_size, void* d_ws, size_t ws_size,
                              hipStream_t stream) {
  const float* x     = (const float*)d_in[0];
  const float* mask  = (const float*)d_in[1];
  const float* lnw1  = (const float*)d_in[2];
  const float* lnb1  = (const float*)d_in[3];
  const float* Wlp   = (const float*)d_in[4];
  const float* blp   = (const float*)d_in[5];
  const float* Wrp   = (const float*)d_in[6];
  const float* brp   = (const float*)d_in[7];
  const float* Wlg   = (const float*)d_in[8];
  const float* blg   = (const float*)d_in[9];
  const float* Wrg   = (const float*)d_in[10];
  const float* brg   = (const float*)d_in[11];
  const float* Wog   = (const float*)d_in[12];
  const float* bog   = (const float*)d_in[13];
  const float* lnw2  = (const float*)d_in[14];
  const float* lnb2  = (const float*)d_in[15];
  const float* Wout  = (const float*)d_in[16];
  const float* bout  = (const float*)d_in[17];

  unsigned short* leftT  = (unsigned short*)d_ws;
  unsigned short* rightT = leftT + (size_t)33554432;
  unsigned short* triT   = rightT + (size_t)33554432;
  unsigned short* wt     = triT + (size_t)33554432;   // 6*64*APAD bf16

  k_prep<<<6, 256, 0, stream>>>(Wlp, Wrp, Wlg, Wrg, Wog, Wout, wt);
  k1_proj<<<8192, 256, 0, stream>>>(x, mask, lnw1, lnb1, blp, brp, blg, brg,
                                    wt, leftT, rightT);
  k2_gemm<<<2048, 256, 0, stream>>>(leftT, rightT, triT);
  k3_out<<<8192, 256, 0, stream>>>(triT, x, lnw1, lnb1, bog, lnw2, lnb2, bout,
                                   wt, (float*)d_out);
}

// Round 6
// 242.494 us; speedup vs baseline: 1.7699x; 1.0287x over previous
//
#include <hip/hip_runtime.h>
#include <cstdint>

typedef float f32x4 __attribute__((ext_vector_type(4)));
typedef short s16x8 __attribute__((ext_vector_type(8)));

#define APAD 72   // padded row (bf16 elems): 144 B rows, 2-way-conflict floor

__device__ __forceinline__ unsigned short f2bf(float f) {
  union { float f; uint32_t u; } v; v.f = f;
  uint32_t u = v.u;
  u += 0x7fffu + ((u >> 16) & 1u);
  return (unsigned short)(u >> 16);
}
__device__ __forceinline__ float bf2f(unsigned short h) {
  union { uint32_t u; float f; } v; v.u = ((uint32_t)h) << 16;
  return v.f;
}
// packed f32x2 -> bf16x2 (lo = a, hi = b), single VALU op
__device__ __forceinline__ uint32_t pkbf(float a, float b) {
  uint32_t r;
  asm("v_cvt_pk_bf16_f32 %0, %1, %2" : "=v"(r) : "v"(a), "v"(b));
  return r;
}
__device__ __forceinline__ float sigmoidf_(float x) {
  return 1.0f / (1.0f + __expf(-x));
}
__device__ __forceinline__ f32x4 zero4() {
  f32x4 z = {0.f, 0.f, 0.f, 0.f};
  return z;
}
__device__ __forceinline__ void gl_lds16(const void* g, void* l) {
  __builtin_amdgcn_global_load_lds(
      (const __attribute__((address_space(1))) uint32_t*)g,
      (__attribute__((address_space(3))) uint32_t*)l, 16, 0, 0);
}

// ---------------------------------------------------------------------------
// prep: transpose 6 weight matrices [k][n] fp32 -> wt bf16 [m][n][APAD]
// ---------------------------------------------------------------------------
__global__ __launch_bounds__(256) void k_prep(
    const float* __restrict__ Wlp, const float* __restrict__ Wrp,
    const float* __restrict__ Wlg, const float* __restrict__ Wrg,
    const float* __restrict__ Wog, const float* __restrict__ Wout,
    unsigned short* __restrict__ wt) {
  const float* srcs[6] = {Wlp, Wrp, Wlg, Wrg, Wog, Wout};
  const int m = blockIdx.x;
  const float* W = srcs[m];
  const int t = threadIdx.x;
  for (int e = t; e < 64 * APAD; e += 256) {
    const int n = e / APAD, k = e - n * APAD;
    wt[m * (64 * APAD) + e] = (k < 64) ? f2bf(W[k * 64 + n]) : (unsigned short)0;
  }
}

// ---------------------------------------------------------------------------
// k1: x = LN(in); left=(x@Wlp+blp)*mask*sig(x@Wlg+blg); right analog.
// Wave w = (pair = w>>1 selects left/right, ch = w&1 selects col half).
// Weights held in VGPRs, loaded once before the barrier.
// ---------------------------------------------------------------------------
__global__ __launch_bounds__(256, 4) void k1_proj(
    const float* __restrict__ xin, const float* __restrict__ mask,
    const float* __restrict__ lnw, const float* __restrict__ lnb,
    const float* __restrict__ blp, const float* __restrict__ brp,
    const float* __restrict__ blg, const float* __restrict__ brg,
    const unsigned short* __restrict__ wt,
    unsigned short* __restrict__ leftT, unsigned short* __restrict__ rightT) {
  __shared__ unsigned short A[64 * APAD];
  __shared__ unsigned short TL[64 * APAD];
  __shared__ unsigned short TR[64 * APAD];
  const int tid = threadIdx.x, lane = tid & 63, w = tid >> 6;
  const int bid = blockIdx.x;
  const int b = bid >> 12;
  const int i = (bid >> 3) & 511;
  const int k0 = (bid & 7) << 6;

  // ---- per-wave weight fragments -> VGPRs (hoisted; hidden under LN) ----
  const int pair = w >> 1, ch = w & 1;
  const int kh8 = (lane >> 4) << 3;
  s16x8 wp[2][2], wg[2][2];
  float bPv[2], bGv[2];
  {
    const unsigned short* wtP = wt + (size_t)pair * (64 * APAD);
    const unsigned short* wtG = wt + (size_t)(2 + pair) * (64 * APAD);
    const float* bP = pair ? brp : blp;
    const float* bG = pair ? brg : blg;
#pragma unroll
    for (int nf2 = 0; nf2 < 2; ++nf2) {
      const int n = ch * 32 + nf2 * 16 + (lane & 15);
      const unsigned short* pp = wtP + n * APAD + kh8;
      const unsigned short* pg = wtG + n * APAD + kh8;
      wp[nf2][0] = *(const s16x8*)pp;  wp[nf2][1] = *(const s16x8*)(pp + 32);
      wg[nf2][0] = *(const s16x8*)pg;  wg[nf2][1] = *(const s16x8*)(pg + 32);
      bPv[nf2] = bP[n];  bGv[nf2] = bG[n];
    }
  }

  // ---- load x rows + layernorm (4 threads per row, 16 ch each) ----
  const int p = tid >> 2, q = tid & 3;
  const float* xrow = xin + (((size_t)b * 512 + i) * 512 + k0 + p) * 64 + q * 16;
  f32x4 xv[4];
#pragma unroll
  for (int u = 0; u < 4; ++u) xv[u] = ((const f32x4*)xrow)[u];
  float s1 = 0.f, s2 = 0.f;
#pragma unroll
  for (int u = 0; u < 4; ++u)
#pragma unroll
    for (int e = 0; e < 4; ++e) { float t = xv[u][e]; s1 += t; s2 += t * t; }
  s1 += __shfl_xor(s1, 1); s2 += __shfl_xor(s2, 1);
  s1 += __shfl_xor(s1, 2); s2 += __shfl_xor(s2, 2);
  const float mu = s1 * 0.015625f;
  const float rs = rsqrtf(s2 * 0.015625f - mu * mu + 1e-5f);
  {
    uint32_t pk[8];
#pragma unroll
    for (int u = 0; u < 4; ++u) {
      f32x4 wv = ((const f32x4*)(lnw + q * 16))[u];
      f32x4 bv = ((const f32x4*)(lnb + q * 16))[u];
#pragma unroll
      for (int e2 = 0; e2 < 2; ++e2) {
        pk[u * 2 + e2] = pkbf((xv[u][2 * e2] - mu) * rs * wv[2 * e2] + bv[2 * e2],
                              (xv[u][2 * e2 + 1] - mu) * rs * wv[2 * e2 + 1] + bv[2 * e2 + 1]);
      }
    }
    uint32_t* a32 = (uint32_t*)&A[p * APAD + q * 16];
#pragma unroll
    for (int u = 0; u < 8; ++u) a32[u] = pk[u];
  }
  const float mval = mask[b * 512 + i];
  __syncthreads();

  // ---- MFMA + wave-local combine + transpose ----
  const int fr4 = (lane >> 4) << 2;
  unsigned short* T = pair ? TR : TL;
#pragma unroll
  for (int mf = 0; mf < 4; ++mf) {
    const int ar = (mf * 16 + (lane & 15)) * APAD + kh8;
    const s16x8 a0 = *(const s16x8*)&A[ar];
    const s16x8 a1 = *(const s16x8*)&A[ar + 32];
    f32x4 accP[2], accG[2];
#pragma unroll
    for (int nf2 = 0; nf2 < 2; ++nf2) {
      accP[nf2] = zero4(); accG[nf2] = zero4();
      accP[nf2] = __builtin_amdgcn_mfma_f32_16x16x32_bf16(a0, wp[nf2][0], accP[nf2], 0, 0, 0);
      accP[nf2] = __builtin_amdgcn_mfma_f32_16x16x32_bf16(a1, wp[nf2][1], accP[nf2], 0, 0, 0);
      accG[nf2] = __builtin_amdgcn_mfma_f32_16x16x32_bf16(a0, wg[nf2][0], accG[nf2], 0, 0, 0);
      accG[nf2] = __builtin_amdgcn_mfma_f32_16x16x32_bf16(a1, wg[nf2][1], accG[nf2], 0, 0, 0);
    }
    const int prow = mf * 16 + fr4;
#pragma unroll
    for (int nf2 = 0; nf2 < 2; ++nf2) {
      const int n = ch * 32 + nf2 * 16 + (lane & 15);
      const float bl = bPv[nf2], bg = bGv[nf2];
      float v0 = (accP[nf2][0] + bl) * mval * sigmoidf_(accG[nf2][0] + bg);
      float v1 = (accP[nf2][1] + bl) * mval * sigmoidf_(accG[nf2][1] + bg);
      float v2 = (accP[nf2][2] + bl) * mval * sigmoidf_(accG[nf2][2] + bg);
      float v3 = (accP[nf2][3] + bl) * mval * sigmoidf_(accG[nf2][3] + bg);
      *(uint32_t*)&T[n * APAD + prow] = pkbf(v0, v1);
      *(uint32_t*)&T[n * APAD + prow + 2] = pkbf(v2, v3);
    }
  }
  __syncthreads();

  // ---- coalesced stores of both transposed tiles ----
  {
    const int sn = tid >> 2, sq = tid & 3;
    const size_t gbase = (((size_t)b * 64 + sn) * 512 + i) * 512 + k0 + sq * 16;
    const uint32_t* sl = (const uint32_t*)&TL[sn * APAD + sq * 16];
    const uint32_t* sr = (const uint32_t*)&TR[sn * APAD + sq * 16];
    uint32_t* dl = (uint32_t*)(leftT + gbase);
    uint32_t* dr = (uint32_t*)(rightT + gbase);
#pragma unroll
    for (int u = 0; u < 8; ++u) dl[u] = sl[u];
#pragma unroll
    for (int u = 0; u < 8; ++u) dr[u] = sr[u];
  }
}

// ---------------------------------------------------------------------------
// k2: triT[b,c,i,j] = sum_k leftT[b,c,i,k] * rightT[b,c,j,k]
// BK=32 double-buffer: LDS 32 KB -> 4 blocks/CU (was 64 KB -> 2, Occ 9.6%).
// Swizzle for 4-slot rows: physical slot s_p of row r holds logical s_p^(r&3);
// linear LDS dest + pre-swizzled global source + XOR read (rule #21).
// ---------------------------------------------------------------------------
__global__ __launch_bounds__(256, 4) void k2_gemm(
    const unsigned short* __restrict__ leftT,
    const unsigned short* __restrict__ rightT,
    unsigned short* __restrict__ triT) {
  __shared__ __align__(16) unsigned short S[4 * 4096];   // 32 KB: [buf][A/B][128*32]
  const int tid = threadIdx.x, lane = tid & 63, w = tid >> 6;
  const int bid = blockIdx.x;
  const int sw = ((bid & 7) << 8) | (bid >> 3);
  const int plane = sw >> 4, tile = sw & 15;
  const size_t pb = (size_t)plane * 262144;
  const int i0 = (tile >> 2) << 7, j0 = (tile & 3) << 7;
  const int srow = lane >> 2;                           // 16 rows per 1KB chunk
  const int sk = (((lane & 3) ^ ((lane >> 2) & 3)) << 3); // pre-swizzled k-slot

  f32x4 acc[4][4];
#pragma unroll
  for (int mf = 0; mf < 4; ++mf)
#pragma unroll
    for (int nf = 0; nf < 4; ++nf) acc[mf][nf] = zero4();
  const int wr = (w >> 1) << 6, wc = (w & 1) << 6;

  auto stage = [&](int buf, int kt) {
    const int kk = kt << 5;
#pragma unroll
    for (int it = 0; it < 2; ++it) {
      const int ch = it * 4 + w;                        // 8 chunks of 1 KB each
      const int row = (ch << 4) + srow;
      gl_lds16(leftT + pb + (size_t)(i0 + row) * 512 + kk + sk,
               (char*)S + buf * 16384 + ch * 1024 + lane * 16);
      gl_lds16(rightT + pb + (size_t)(j0 + row) * 512 + kk + sk,
               (char*)S + buf * 16384 + 8192 + ch * 1024 + lane * 16);
    }
  };

  stage(0, 0);
  const int l15 = lane & 15;
  const int kosw = ((lane >> 4) ^ (lane & 3)) << 3;     // logical kgrp ^ (row&3)
  for (int kt = 0; kt < 16; ++kt) {
    __syncthreads();
    if (kt < 15) stage((kt & 1) ^ 1, kt + 1);
    const unsigned short* Ac = S + (kt & 1) * 8192;
    const unsigned short* Bc = Ac + 4096;
    s16x8 af[4], bfr[4];
#pragma unroll
    for (int mf = 0; mf < 4; ++mf)
      af[mf] = *(const s16x8*)&Ac[(wr + mf * 16 + l15) * 32 + kosw];
#pragma unroll
    for (int nf = 0; nf < 4; ++nf)
      bfr[nf] = *(const s16x8*)&Bc[(wc + nf * 16 + l15) * 32 + kosw];
#pragma unroll
    for (int mf = 0; mf < 4; ++mf)
#pragma unroll
      for (int nf = 0; nf < 4; ++nf)
        acc[mf][nf] = __builtin_amdgcn_mfma_f32_16x16x32_bf16(af[mf], bfr[nf], acc[mf][nf], 0, 0, 0);
  }
  __syncthreads();
  // repack 128x128 bf16 into LDS (Tt = whole 32 KB buffer), coalesced store
  unsigned short* Tt = S;
#pragma unroll
  for (int mf = 0; mf < 4; ++mf)
#pragma unroll
    for (int nf = 0; nf < 4; ++nf) {
      const int col = wc + nf * 16 + l15;
#pragma unroll
      for (int r = 0; r < 4; ++r) {
        const int row = wr + mf * 16 + ((lane >> 4) << 2) + r;
        Tt[row * 128 + col] = f2bf(acc[mf][nf][r]);
      }
    }
  __syncthreads();
  {
    const int row = tid >> 1, half = (tid & 1) << 6;
    const uint32_t* src = (const uint32_t*)&Tt[row * 128 + half];
    uint32_t* dst = (uint32_t*)(triT + pb + (size_t)(i0 + row) * 512 + j0 + half);
#pragma unroll
    for (int u = 0; u < 32; ++u) dst[u] = src[u];
  }
}

// ---------------------------------------------------------------------------
// k3: y = LN_out(tri) * sigmoid(LN_in(resid)@Wog+bog); out = y@Wout+bout+resid
// MFMA-D layout is the home layout for LN+gate: lane (j=w*16+l15, hi) owns
// c = hi*4+r+nf*16; tri values read as 4x ds_read_b64 from swizzled Y; stats
// via shfl_xor(16/32); og stays in VGPRs; y written in-place. OG buffer gone.
// OUT32 aliases Y+X (dead) with a read-fence barrier.
// ---------------------------------------------------------------------------
#define OPAD 68   // padded f32 out-tile row
__global__ __launch_bounds__(256, 4) void k3_out(
    const unsigned short* __restrict__ triT,
    const float* __restrict__ resid,
    const float* __restrict__ lnw1, const float* __restrict__ lnb1,
    const float* __restrict__ bog,
    const float* __restrict__ lnw2, const float* __restrict__ lnb2,
    const float* __restrict__ bout,
    const unsigned short* __restrict__ wt,
    float* __restrict__ outp) {
  __shared__ __align__(16) unsigned char smem[36864];
  unsigned short* WTog  = (unsigned short*)smem;            // [64][APAD]
  unsigned short* WTout = (unsigned short*)(smem + 9216);   // [64][APAD]
  unsigned short* Y     = (unsigned short*)(smem + 18432);  // [64][APAD] (swz c)
  unsigned short* X     = (unsigned short*)(smem + 27648);  // [64][APAD]
  float* OUT32 = (float*)(smem + 18432);                    // [64][OPAD] aliases Y,X
  const int tid = threadIdx.x, lane = tid & 63, w = tid >> 6;
  const int bid = blockIdx.x;
  const int b = bid >> 12;
  const int i = (bid >> 3) & 511;
  const int j0 = (bid & 7) << 6;

  // entry: async-stage og^T and out^T (18432 B, contiguous in wt)
  {
    const char* wsrc = (const char*)(wt + (size_t)4 * (64 * APAD));
#pragma unroll
    for (int it = 0; it < 5; ++it) {
      const int off = (it * 256 + tid) * 16;
      if (off < 18432) gl_lds16(wsrc + off, (char*)WTog + off);
    }
  }

  const int j = tid >> 2, q = tid & 3;
  // phase 1: tri tile -> transposed Y[j][c^((j>>4)<<4)]; resid LN -> X
  {
    const int c = tid >> 2;
    const int csw = c ^ (q << 4);        // swizzle value = j>>4 = q here
    const size_t srow = ((size_t)(b * 64 + c) * 512 + i) * 512 + j0 + q * 16;
    union { uint32_t u32[8]; unsigned short s[16]; } uu;
    const uint32_t* s32 = (const uint32_t*)(triT + srow);
#pragma unroll
    for (int u = 0; u < 8; ++u) uu.u32[u] = s32[u];
#pragma unroll
    for (int s = 0; s < 16; ++s) Y[(q * 16 + s) * APAD + csw] = uu.s[s];
  }
  f32x4 rv[4];   // resid row fragment, reused in phase 5
  {
    const float* rrow = resid + (((size_t)b * 512 + i) * 512 + j0 + j) * 64 + q * 16;
#pragma unroll
    for (int u = 0; u < 4; ++u) rv[u] = ((const f32x4*)rrow)[u];
    float s1 = 0.f, s2 = 0.f;
#pragma unroll
    for (int u = 0; u < 4; ++u)
#pragma unroll
      for (int e = 0; e < 4; ++e) { float t = rv[u][e]; s1 += t; s2 += t * t; }
    s1 += __shfl_xor(s1, 1); s2 += __shfl_xor(s2, 1);
    s1 += __shfl_xor(s1, 2); s2 += __shfl_xor(s2, 2);
    const float mu = s1 * 0.015625f;
    const float rs = rsqrtf(s2 * 0.015625f - mu * mu + 1e-5f);
    uint32_t pk[8];
#pragma unroll
    for (int u = 0; u < 4; ++u) {
      f32x4 wv = ((const f32x4*)(lnw1 + q * 16))[u];
      f32x4 bv = ((const f32x4*)(lnb1 + q * 16))[u];
#pragma unroll
      for (int e2 = 0; e2 < 2; ++e2) {
        pk[u * 2 + e2] = pkbf((rv[u][2 * e2] - mu) * rs * wv[2 * e2] + bv[2 * e2],
                              (rv[u][2 * e2 + 1] - mu) * rs * wv[2 * e2 + 1] + bv[2 * e2 + 1]);
      }
    }
    uint32_t* x32 = (uint32_t*)&X[j * APAD + q * 16];
#pragma unroll
    for (int u = 0; u < 8; ++u) x32[u] = pk[u];
  }
  __syncthreads();   // B1 (drains WT staging + Y + X)

  // phase 2 (MFMA-D home layout): stats + og-MFMA (in regs) + y -> Y in-place
  const int l15 = lane & 15, hi = lane >> 4;
  const int jrow = w * 16 + l15;
  const int ybase = jrow * APAD;
  const int kh8 = hi << 3;
  float yv[16];
#pragma unroll
  for (int nf = 0; nf < 4; ++nf) {
    const int pc = (((nf ^ w) & 3) << 4) + (hi << 2);   // phys col of c=nf*16+hi*4
    const uint2 dd = *(const uint2*)&Y[ybase + pc];
    yv[nf * 4 + 0] = bf2f((unsigned short)(dd.x & 0xffff));
    yv[nf * 4 + 1] = bf2f((unsigned short)(dd.x >> 16));
    yv[nf * 4 + 2] = bf2f((unsigned short)(dd.y & 0xffff));
    yv[nf * 4 + 3] = bf2f((unsigned short)(dd.y >> 16));
  }
  float t1 = 0.f, t2 = 0.f;
#pragma unroll
  for (int s = 0; s < 16; ++s) { t1 += yv[s]; t2 += yv[s] * yv[s]; }
  t1 += __shfl_xor(t1, 16); t2 += __shfl_xor(t2, 16);
  t1 += __shfl_xor(t1, 32); t2 += __shfl_xor(t2, 32);
  const float mu2 = t1 * 0.015625f;
  const float rs2 = rsqrtf(t2 * 0.015625f - mu2 * mu2 + 1e-5f);

  float sg[16];
  {
    const s16x8 xb0 = *(const s16x8*)&X[ybase + kh8];
    const s16x8 xb1 = *(const s16x8*)&X[ybase + kh8 + 32];
#pragma unroll
    for (int nf = 0; nf < 4; ++nf) {
      const int wrow = (nf * 16 + l15) * APAD + kh8;
      const s16x8 wa0 = *(const s16x8*)&WTog[wrow];
      const s16x8 wa1 = *(const s16x8*)&WTog[wrow + 32];
      f32x4 aog = zero4();
      aog = __builtin_amdgcn_mfma_f32_16x16x32_bf16(wa0, xb0, aog, 0, 0, 0);
      aog = __builtin_amdgcn_mfma_f32_16x16x32_bf16(wa1, xb1, aog, 0, 0, 0);
      const f32x4 bb4 = *(const f32x4*)(bog + nf * 16 + (hi << 2));
      sg[nf * 4 + 0] = sigmoidf_(aog[0] + bb4[0]);
      sg[nf * 4 + 1] = sigmoidf_(aog[1] + bb4[1]);
      sg[nf * 4 + 2] = sigmoidf_(aog[2] + bb4[2]);
      sg[nf * 4 + 3] = sigmoidf_(aog[3] + bb4[3]);
    }
  }
#pragma unroll
  for (int nf = 0; nf < 4; ++nf) {
    const f32x4 wv = *(const f32x4*)(lnw2 + nf * 16 + (hi << 2));
    const f32x4 bv = *(const f32x4*)(lnb2 + nf * 16 + (hi << 2));
    const float y0 = ((yv[nf * 4 + 0] - mu2) * rs2 * wv[0] + bv[0]) * sg[nf * 4 + 0];
    const float y1 = ((yv[nf * 4 + 1] - mu2) * rs2 * wv[1] + bv[1]) * sg[nf * 4 + 1];
    const float y2 = ((yv[nf * 4 + 2] - mu2) * rs2 * wv[2] + bv[2]) * sg[nf * 4 + 2];
    const float y3 = ((yv[nf * 4 + 3] - mu2) * rs2 * wv[3] + bv[3]) * sg[nf * 4 + 3];
    uint2 o;
    o.x = pkbf(y0, y1);
    o.y = pkbf(y2, y3);
    const int pc = (((nf ^ w) & 3) << 4) + (hi << 2);
    *(uint2*)&Y[ybase + pc] = o;
  }
  __syncthreads();   // B2

  // phase 4: out = Y @ Wout + bout -> OUT32 (aliases Y+X; read-fence barrier)
  {
    const int xsw = (w & 3) << 4;
    const s16x8 a0 = *(const s16x8*)&Y[ybase + (kh8 ^ xsw)];
    const s16x8 a1 = *(const s16x8*)&Y[ybase + ((32 + kh8) ^ xsw)];
    s16x8 wb0[4], wb1[4];
#pragma unroll
    for (int nf = 0; nf < 4; ++nf) {
      const int brow = (nf * 16 + l15) * APAD + kh8;
      wb0[nf] = *(const s16x8*)&WTout[brow];
      wb1[nf] = *(const s16x8*)&WTout[brow + 32];
    }
    __syncthreads();   // B3: all Y reads complete before OUT32 overwrites
    f32x4 ao[4];
#pragma unroll
    for (int nf = 0; nf < 4; ++nf) {
      ao[nf] = zero4();
      ao[nf] = __builtin_amdgcn_mfma_f32_16x16x32_bf16(a0, wb0[nf], ao[nf], 0, 0, 0);
      ao[nf] = __builtin_amdgcn_mfma_f32_16x16x32_bf16(a1, wb1[nf], ao[nf], 0, 0, 0);
    }
#pragma unroll
    for (int nf = 0; nf < 4; ++nf) {
      const int n = nf * 16 + l15;
      const float bo = bout[n];
#pragma unroll
      for (int r = 0; r < 4; ++r) {
        const int prow = w * 16 + (hi << 2) + r;
        OUT32[prow * OPAD + n] = ao[nf][r] + bo;
      }
    }
  }
  __syncthreads();   // B4

  // phase 5: coalesced residual add (resid from regs) + store
  {
    const size_t gb = (((size_t)b * 512 + i) * 512 + j0 + j) * 64 + q * 16;
    float* op = outp + gb;
#pragma unroll
    for (int u = 0; u < 4; ++u) {
      f32x4 ov = ((const f32x4*)&OUT32[j * OPAD + q * 16])[u];
      ((f32x4*)op)[u] = ov + rv[u];
    }
  }
}

// ---------------------------------------------------------------------------
extern "C" void kernel_launch(void* const* d_in, const int* in_sizes, int n_in,
                              void* d_out, int out_size, void* d_ws, size_t ws_size,
                              hipStream_t stream) {
  const float* x     = (const float*)d_in[0];
  const float* mask  = (const float*)d_in[1];
  const float* lnw1  = (const float*)d_in[2];
  const float* lnb1  = (const float*)d_in[3];
  const float* Wlp   = (const float*)d_in[4];
  const float* blp   = (const float*)d_in[5];
  const float* Wrp   = (const float*)d_in[6];
  const float* brp   = (const float*)d_in[7];
  const float* Wlg   = (const float*)d_in[8];
  const float* blg   = (const float*)d_in[9];
  const float* Wrg   = (const float*)d_in[10];
  const float* brg   = (const float*)d_in[11];
  const float* Wog   = (const float*)d_in[12];
  const float* bog   = (const float*)d_in[13];
  const float* lnw2  = (const float*)d_in[14];
  const float* lnb2  = (const float*)d_in[15];
  const float* Wout  = (const float*)d_in[16];
  const float* bout  = (const float*)d_in[17];

  unsigned short* leftT  = (unsigned short*)d_ws;
  unsigned short* rightT = leftT + (size_t)33554432;
  unsigned short* triT   = rightT + (size_t)33554432;
  unsigned short* wt     = triT + (size_t)33554432;   // 6*64*APAD bf16

  k_prep<<<6, 256, 0, stream>>>(Wlp, Wrp, Wlg, Wrg, Wog, Wout, wt);
  k1_proj<<<8192, 256, 0, stream>>>(x, mask, lnw1, lnb1, blp, brp, blg, brg,
                                    wt, leftT, rightT);
  k2_gemm<<<2048, 256, 0, stream>>>(leftT, rightT, triT);
  k3_out<<<8192, 256, 0, stream>>>(triT, x, lnw1, lnb1, bog, lnw2, lnb2, bout,
                                   wt, (float*)d_out);
}